// Round 11
// baseline (318.444 us; speedup 1.0000x reference)
//
#include <hip/hip_runtime.h>
#include <math.h>

// Problem constants (from reference setup_inputs)
#define NN    5000      // nodes
#define NE    80000     // edges
#define NB    32        // batch
#define DIN   16        // input feat
#define CH    64        // conv channels
#define KPOOL 30
#define FTOT  208      // 16 + 3*64
#define FLATW 6241     // KPOOL*FTOT + 1
#define NH    128      // MLP hidden
#define NG    8        // batch groups for CIN64 layer (one per XCD)
#define GB    4        // batches per group (h1/h2 layout)
#define NPB   16       // nodes per block (4 per wave)
#define NCHUNK 313     // node chunks (blocks per group)
#define NPAD  5008     // perm array size
#define NEPAD (NE + 4 * NN)   // CSR rows padded to multiple of 4
#define NSLOT 32       // stats atomic-spread slots

// Journal: R19 ordering / R20+R24 occupancy: dead. R21 CSR rotate: neutral.
// R22 act-hoist: -43% VALU -> -5% dur. R26 serial-merge: 354 -> 348.6.
// R27/28 batch-half: L2-fit proven (FETCH 114->13MB) but pass-doubling loses:
// TIME PER PASS ~ # DEPENDENT GATHER ITERATIONS. R29 wide CIN64 rows: VGPR
// cliff (16 f4 live -> serialized loads) + 10MB/2-XCD thrash -> 96us. CIN64
// floor = G8/1KB rows at ~71.4us. R30: conv2 killed algebraically (z/score/
// gather-agg): 348.6 -> 316.5. R31 (this): layer-0 was the 2nd-biggest kernel
// (~60-70us, worst config: 4-in-flight sequential). Move xt to G4 (512B rows,
// 8 batches): iterations HALVE (200K->100K) and pair-interleave doubles
// in-flight (4->8). Rows tiny (f2/lane) -> no R9 VGPR cliff; slab 2.56MB
// L2-fits across 2 XCDs. h1 output stays (G8,N,4,64) -> CIN64 untouched.

// ---------------- setup kernels ----------------

__global__ void k_init(float* deg, int* counts, float* stats, float* hm, int* perm) {
    int i = blockIdx.x * 256 + threadIdx.x;
    if (i < NN) { deg[i] = 1.0f; counts[i] = 0; }   // deg starts at self-loop value 1
    if (i < 2 * NSLOT * 128) stats[i] = 0.0f;       // [2 layers][32 slots][128]
    if (i < 4096) hm[i] = 0.0f;
    if (i >= NN && i < NPAD) perm[i] = NN;          // tail -> invalid marker
}

#define NEB 313
__global__ void k_edges(const float* __restrict__ attr, const int* __restrict__ erow,
                        float* deg, int* counts) {
    int e = blockIdx.x * 256 + threadIdx.x;
    if (e < NE) {
        int r = erow[e];
        atomicAdd(&deg[r], attr[e]);
        atomicAdd(&counts[r], 1);
    }
}

// merged concurrent phase: block 0 = prefix scan, block 1 = counting sort,
// blocks 2.. = x transpose to (G4,N,8,16) (serial roles hide under transpose).
__global__ __launch_bounds__(1024) void k_phase1(
        const int* __restrict__ counts, const float* __restrict__ deg,
        int* rowptr, int* cursor, float* dinv, int* perm,
        const float* __restrict__ x, float* __restrict__ xt) {
    __shared__ int wsum[16], woff[16];
    __shared__ int carry_sh;
    __shared__ int hist[256];
    int t = threadIdx.x;
    if (blockIdx.x >= 2) {
        int idx = (blockIdx.x - 2) * 1024 + t;
        if (idx >= NB * NN) return;
        int b = idx / NN, n = idx % NN;
        int g4 = b >> 3, bi8 = b & 7;
        const float4* src = (const float4*)(x + (size_t)idx * DIN);
        float4* dst = (float4*)(xt + (((size_t)g4 * NN + n) * 8 + bi8) * DIN);
        dst[0] = src[0]; dst[1] = src[1]; dst[2] = src[2]; dst[3] = src[3];
        return;
    }
    if (blockIdx.x == 0) {
        int lane = t & 63, wid = t >> 6;
        if (t == 0) carry_sh = 0;
        __syncthreads();
        for (int base = 0; base < NN; base += 1024) {
            int carry = carry_sh;
            int i = base + t;
            int v = 0;
            if (i < NN) {
                v = (counts[i] + 3) & ~3;
                dinv[i] = 1.0f / sqrtf(deg[i]);   // deg >= 1 always
            }
            int s = v;
#pragma unroll
            for (int off = 1; off < 64; off <<= 1) {
                int o = __shfl_up(s, off);
                if (lane >= off) s += o;
            }
            if (lane == 63) wsum[wid] = s;
            __syncthreads();
            if (t < 16) {
                int w = wsum[t];
#pragma unroll
                for (int off = 1; off < 16; off <<= 1) {
                    int o = __shfl_up(w, off);
                    if (t >= off) w += o;
                }
                woff[t] = w;
            }
            __syncthreads();
            int inc = s + (wid > 0 ? woff[wid - 1] : 0) + carry;
            if (i < NN) {
                rowptr[i + 1] = inc;
                cursor[i] = inc - v;
            }
            if (t == 1023) carry_sh = carry + woff[15];
            __syncthreads();
        }
        if (t == 0) rowptr[0] = 0;
    } else {
        if (t < 256) hist[t] = 0;
        __syncthreads();
        for (int i = t; i < NN; i += 1024) {
            int b = 255 - min(((counts[i] + 3) & ~3) >> 2, 255);
            atomicAdd(&hist[b], 1);
        }
        __syncthreads();
        int mycnt = (t < 256) ? hist[t] : 0;
        for (int off = 1; off < 256; off <<= 1) {
            int v = (t < 256 && t >= off) ? hist[t - off] : 0;
            __syncthreads();
            if (t < 256) hist[t] += v;
            __syncthreads();
        }
        if (t < 256) hist[t] -= mycnt;
        __syncthreads();
        for (int i = t; i < NN; i += 1024) {
            int b = 255 - min(((counts[i] + 3) & ~3) >> 2, 255);
            int pos = atomicAdd(&hist[b], 1);
            perm[pos] = i;
        }
    }
}

__global__ __launch_bounds__(1024) void k_build(
        const int* __restrict__ erow, const int* __restrict__ ecol,
        const float* __restrict__ attr, const float* __restrict__ dinv,
        const int* __restrict__ counts, const int* __restrict__ rowptr,
        int* cursor, int* csr_col, float* csr_nv) {
    int t = blockIdx.x * 1024 + threadIdx.x;
    if (t < NE) {
        int r = erow[t], c = ecol[t];
        int pos = atomicAdd(&cursor[r], 1);
        csr_col[pos] = c;
        csr_nv[pos] = dinv[r] * attr[t] * dinv[c];
    } else if (t - NE < NN) {
        int i = t - NE;
        int cnt = counts[i];
        int pcnt = (cnt + 3) & ~3;
        int base = rowptr[i + 1] - pcnt;
        for (int p = base + cnt; p < base + pcnt; ++p) { csr_col[p] = i; csr_nv[p] = 0.0f; }
    }
}

// ---------------- helpers ----------------
__device__ __forceinline__ float4 actv(float4 v, float4 s, float4 t) {
    v.x = fmaxf(fmaf(v.x, s.x, t.x), 0.f);
    v.y = fmaxf(fmaf(v.y, s.y, t.y), 0.f);
    v.z = fmaxf(fmaf(v.z, s.z, t.z), 0.f);
    v.w = fmaxf(fmaf(v.w, s.w, t.w), 0.f);
    return v;
}
__device__ __forceinline__ void fma4(float4& a, float w, float4 v) {
    a.x = fmaf(w, v.x, a.x); a.y = fmaf(w, v.y, a.y);
    a.z = fmaf(w, v.z, a.z); a.w = fmaf(w, v.w, a.w);
}
__device__ __forceinline__ void fma2(float2& a, float w, float2 v) {
    a.x = fmaf(w, v.x, a.x); a.y = fmaf(w, v.y, a.y);
}

// ---------------- layer 0 (CIN=16, G4): xt (G4,N,8,16) -> h1 (G8,N,4,64) ----
// R31: 512B rows, pair-interleaved (8 float2 gathers in flight), 4 groups x
// 25K bundles (half of old). Stage 2: o[8] per lane (8 batches), K=16 GEMM;
// writes h1 in the G8 layout the CIN64 layer expects.
__global__ __launch_bounds__(256) void k_l16(
        const float* __restrict__ in,
        const float* __restrict__ W, const float* __restrict__ bias,
        const int* __restrict__ rowptr, const int* __restrict__ csr_col,
        const float* __restrict__ csr_nv, const float* __restrict__ dinv,
        const int* __restrict__ perm,
        float* __restrict__ out, float* __restrict__ stats) {
    const int ALS = 18;
    __shared__ float As[4 * 32 * ALS];   // 9216 B
    int tid = threadIdx.x;
    int wid = tid >> 6, lane = tid & 63;
    int g4 = blockIdx.x & 3;
    int base = (blockIdx.x >> 2) * NPB + wid * 4;
    float* Aw = As + wid * 32 * ALS;
    const int4 pid = *(const int4*)(perm + base);

    const float2* __restrict__ in2 = (const float2*)in + (size_t)g4 * NN * 64; // row = 64 f2
    int bi8 = lane >> 3, chp = lane & 7;   // (batch-of-8, ch-pair)

#pragma unroll
    for (int pr = 0; pr < 2; ++pr) {
        int id0 = (pr == 0) ? pid.x : pid.z;
        int id1 = (pr == 0) ? pid.y : pid.w;
        bool vn0 = id0 < NN, vn1 = id1 < NN;
        int rc0 = vn0 ? id0 : 0, rc1 = vn1 ? id1 : 0;
        float dd0 = dinv[rc0]; dd0 *= dd0;
        float dd1 = dinv[rc1]; dd1 *= dd1;
        float2 a0 = {0.f, 0.f}, a1 = {0.f, 0.f};
        {
            float2 v0 = in2[(size_t)rc0 * 64 + lane];
            float2 v1 = in2[(size_t)rc1 * 64 + lane];
            if (vn0) { a0.x = dd0 * v0.x; a0.y = dd0 * v0.y; }
            if (vn1) { a1.x = dd1 * v1.x; a1.y = dd1 * v1.y; }
        }
        int p0a = rowptr[rc0], na = vn0 ? (rowptr[rc0 + 1] - p0a) >> 2 : 0;
        int p0b = rowptr[rc1], nbv = vn1 ? (rowptr[rc1 + 1] - p0b) >> 2 : 0;
        int mx = max(na, nbv);
        for (int bb = 0; bb < mx; ++bb) {
            int ea = min(p0a + 4 * bb, NEPAD - 4);
            int eb = min(p0b + 4 * bb, NEPAD - 4);
            bool va = bb < na, vb = bb < nbv;
            int4   ca = *(const int4*)(csr_col + ea);
            float4 wa = *(const float4*)(csr_nv + ea);
            int4   cb = *(const int4*)(csr_col + eb);
            float4 wb = *(const float4*)(csr_nv + eb);
            if (!va) { wa.x = 0.f; wa.y = 0.f; wa.z = 0.f; wa.w = 0.f;
                       ca.x = 0; ca.y = 0; ca.z = 0; ca.w = 0; }   // poisoned tail
            if (!vb) { wb.x = 0.f; wb.y = 0.f; wb.z = 0.f; wb.w = 0.f;
                       cb.x = 0; cb.y = 0; cb.z = 0; cb.w = 0; }
            float2 u0 = in2[(size_t)ca.x * 64 + lane];
            float2 u1 = in2[(size_t)ca.y * 64 + lane];
            float2 u2 = in2[(size_t)ca.z * 64 + lane];
            float2 u3 = in2[(size_t)ca.w * 64 + lane];
            float2 t0 = in2[(size_t)cb.x * 64 + lane];
            float2 t1 = in2[(size_t)cb.y * 64 + lane];
            float2 t2 = in2[(size_t)cb.z * 64 + lane];
            float2 t3 = in2[(size_t)cb.w * 64 + lane];
            fma2(a0, wa.x, u0);
            fma2(a0, wa.y, u1);
            fma2(a0, wa.z, u2);
            fma2(a0, wa.w, u3);
            fma2(a1, wb.x, t0);
            fma2(a1, wb.y, t1);
            fma2(a1, wb.z, t2);
            fma2(a1, wb.w, t3);
        }
        *(float2*)(Aw + ((2 * pr + 0) * 8 + bi8) * ALS + chp * 2) = a0;
        *(float2*)(Aw + ((2 * pr + 1) * 8 + bi8) * ALS + chp * 2) = a1;
    }
    // NO barrier: stage 2 reads only this wave's Aw slice.

    int colq = lane & 15, rowq = lane >> 4;
    int node = (rowq == 0) ? pid.x : (rowq == 1) ? pid.y : (rowq == 2) ? pid.z : pid.w;

    const float4* __restrict__ W4 = (const float4*)W;
    float4 bb4 = ((const float4*)bias)[colq];
    float4 o[8];
#pragma unroll
    for (int i = 0; i < 8; ++i) o[i] = bb4;
#pragma unroll
    for (int k = 0; k < 16; ++k) {
        float4 w4 = W4[k * 16 + colq];
#pragma unroll
        for (int i = 0; i < 8; ++i)
            fma4(o[i], Aw[(rowq * 8 + i) * ALS + k], w4);
    }
    if (node < NN) {
#pragma unroll
        for (int i = 0; i < 8; ++i) {
            int g8 = g4 * 2 + (i >> 2);
            float4* op = (float4*)(out + (((size_t)g8 * NN + node) * 4 + (i & 3)) * 64);
            op[colq] = o[i];
        }
    }

    // stats (layer 0): lane sums its 8 batches; shfl sums over nodes
    float4 s4 = {0,0,0,0}, q4 = {0,0,0,0};
    if (node < NN) {
#pragma unroll
        for (int i = 0; i < 8; ++i) {
            s4.x += o[i].x; s4.y += o[i].y; s4.z += o[i].z; s4.w += o[i].w;
            q4.x = fmaf(o[i].x, o[i].x, q4.x); q4.y = fmaf(o[i].y, o[i].y, q4.y);
            q4.z = fmaf(o[i].z, o[i].z, q4.z); q4.w = fmaf(o[i].w, o[i].w, q4.w);
        }
    }
    s4.x += __shfl_xor(s4.x, 16); s4.y += __shfl_xor(s4.y, 16);
    s4.z += __shfl_xor(s4.z, 16); s4.w += __shfl_xor(s4.w, 16);
    q4.x += __shfl_xor(q4.x, 16); q4.y += __shfl_xor(q4.y, 16);
    q4.z += __shfl_xor(q4.z, 16); q4.w += __shfl_xor(q4.w, 16);
    s4.x += __shfl_xor(s4.x, 32); s4.y += __shfl_xor(s4.y, 32);
    s4.z += __shfl_xor(s4.z, 32); s4.w += __shfl_xor(s4.w, 32);
    q4.x += __shfl_xor(q4.x, 32); q4.y += __shfl_xor(q4.y, 32);
    q4.z += __shfl_xor(q4.z, 32); q4.w += __shfl_xor(q4.w, 32);
    __syncthreads();   // all waves done with As -> reuse as scratch
    if (lane < 16) {
        float* S = As + wid * 128;
        *(float4*)(S + lane * 8) = s4;
        *(float4*)(S + lane * 8 + 4) = q4;
    }
    __syncthreads();
    if (tid < 64) {
        int cq = tid >> 2, comp = tid & 3;
        float s = 0.f, q = 0.f;
#pragma unroll
        for (int w = 0; w < 4; ++w) {
            s += As[w * 128 + cq * 8 + comp];
            q += As[w * 128 + cq * 8 + 4 + comp];
        }
        float* sl = stats + (blockIdx.x & (NSLOT - 1)) * 128;
        atomicAdd(&sl[tid], s);
        atomicAdd(&sl[64 + tid], q);
    }
}

// ---------------- fused CIN64 GCN layer (R0 proven base — at gather roofline)
__global__ __launch_bounds__(256) void k_l64(
        const float* __restrict__ in, const float* __restrict__ bnstats,
        const float* __restrict__ gamma, const float* __restrict__ beta,
        const float* __restrict__ W, const float* __restrict__ bias,
        const int* __restrict__ rowptr, const int* __restrict__ csr_col,
        const float* __restrict__ csr_nv, const float* __restrict__ dinv,
        const int* __restrict__ perm,
        float* __restrict__ out, float* __restrict__ stats) {
    const int ALS = 68;
    __shared__ float As[4 * 16 * ALS];
    __shared__ float stl[128];
    int tid = threadIdx.x;
    int wid = tid >> 6, lane = tid & 63;
    int g = blockIdx.x & 7;                      // XCD round-robin
    int base = (blockIdx.x >> 3) * NPB + wid * 4;
    float* Aw = As + wid * 16 * ALS;
    const int4 pid = *(const int4*)(perm + base);   // 4 node ids (degree-sorted)

    if (tid < 64) {
        float su = 0.f, qu = 0.f;
#pragma unroll
        for (int s = 0; s < NSLOT; ++s) {
            su += bnstats[s * 128 + tid];
            qu += bnstats[s * 128 + 64 + tid];
        }
        const float inv = 1.0f / (float)(NB * NN);
        float mu = su * inv;
        float var = qu * inv - mu * mu;
        float sc = gamma[tid] / sqrtf(var + 1e-5f);
        stl[tid] = sc;
        stl[64 + tid] = fmaf(-mu, sc, beta[tid]);
    }
    __syncthreads();

    const float4* __restrict__ in4 = (const float4*)in + (size_t)g * NN * 64;
    int c4 = lane & 15, bi = lane >> 4;
    float4 sv = ((const float4*)stl)[c4];
    float4 tv = ((const float4*)(stl + 64))[c4];
#pragma unroll
    for (int pr = 0; pr < 2; ++pr) {
        int id0 = (pr == 0) ? pid.x : pid.z;
        int id1 = (pr == 0) ? pid.y : pid.w;
        bool vn0 = id0 < NN, vn1 = id1 < NN;
        int rc0 = vn0 ? id0 : 0, rc1 = vn1 ? id1 : 0;
        float dd0 = dinv[rc0]; dd0 *= dd0;
        float dd1 = dinv[rc1]; dd1 *= dd1;
        float4 a0 = {0.f,0.f,0.f,0.f}, a1 = {0.f,0.f,0.f,0.f};
        {
            float4 v0 = actv(in4[(size_t)rc0 * 64 + lane], sv, tv);
            float4 v1 = actv(in4[(size_t)rc1 * 64 + lane], sv, tv);
            if (vn0) { a0.x = dd0 * v0.x; a0.y = dd0 * v0.y; a0.z = dd0 * v0.z; a0.w = dd0 * v0.w; }
            if (vn1) { a1.x = dd1 * v1.x; a1.y = dd1 * v1.y; a1.z = dd1 * v1.z; a1.w = dd1 * v1.w; }
        }
        int p0a = rowptr[rc0], na = vn0 ? (rowptr[rc0 + 1] - p0a) >> 2 : 0;
        int p0b = rowptr[rc1], nbv = vn1 ? (rowptr[rc1 + 1] - p0b) >> 2 : 0;
        int mx = max(na, nbv);
        for (int bb = 0; bb < mx; ++bb) {
            int ea = min(p0a + 4 * bb, NEPAD - 4);
            int eb = min(p0b + 4 * bb, NEPAD - 4);
            bool va = bb < na, vb = bb < nbv;
            int4   ca = *(const int4*)(csr_col + ea);
            float4 wa = *(const float4*)(csr_nv + ea);
            int4   cb = *(const int4*)(csr_col + eb);
            float4 wb = *(const float4*)(csr_nv + eb);
            if (!va) { wa.x = 0.f; wa.y = 0.f; wa.z = 0.f; wa.w = 0.f;
                       ca.x = 0; ca.y = 0; ca.z = 0; ca.w = 0; }   // poisoned tail
            if (!vb) { wb.x = 0.f; wb.y = 0.f; wb.z = 0.f; wb.w = 0.f;
                       cb.x = 0; cb.y = 0; cb.z = 0; cb.w = 0; }
            float4 u0 = in4[(size_t)ca.x * 64 + lane];
            float4 u1 = in4[(size_t)ca.y * 64 + lane];
            float4 u2 = in4[(size_t)ca.z * 64 + lane];
            float4 u3 = in4[(size_t)ca.w * 64 + lane];
            float4 t0 = in4[(size_t)cb.x * 64 + lane];
            float4 t1 = in4[(size_t)cb.y * 64 + lane];
            float4 t2 = in4[(size_t)cb.z * 64 + lane];
            float4 t3 = in4[(size_t)cb.w * 64 + lane];
            fma4(a0, wa.x, actv(u0, sv, tv));
            fma4(a0, wa.y, actv(u1, sv, tv));
            fma4(a0, wa.z, actv(u2, sv, tv));
            fma4(a0, wa.w, actv(u3, sv, tv));
            fma4(a1, wb.x, actv(t0, sv, tv));
            fma4(a1, wb.y, actv(t1, sv, tv));
            fma4(a1, wb.z, actv(t2, sv, tv));
            fma4(a1, wb.w, actv(t3, sv, tv));
        }
        *(float4*)(Aw + ((pr * 2 + 0) * 4 + bi) * ALS + c4 * 4) = a0;
        *(float4*)(Aw + ((pr * 2 + 1) * 4 + bi) * ALS + c4 * 4) = a1;
    }
    // NO __syncthreads here: stage 2 reads only this wave's Aw slice.

    int colq = lane & 15, rowq = lane >> 4;
    int node = (rowq == 0) ? pid.x : (rowq == 1) ? pid.y : (rowq == 2) ? pid.z : pid.w;

    // ---- stage 2: per-wave GEMM; thread -> (node rowq, colq) ----
    const float4* __restrict__ W4 = (const float4*)W;
    float4 bb = ((const float4*)bias)[colq];
    float4 o[4];
#pragma unroll
    for (int i = 0; i < 4; ++i) o[i] = bb;
#pragma unroll 8
    for (int k = 0; k < 64; ++k) {
        float4 w4 = W4[k * 16 + colq];
#pragma unroll
        for (int i = 0; i < 4; ++i) {
            float a = Aw[(rowq * 4 + i) * ALS + k];
            fma4(o[i], a, w4);
        }
    }
    if (node < NN) {
        float4* __restrict__ op = (float4*)(out + ((size_t)g * NN + node) * 256);
#pragma unroll
        for (int i = 0; i < 4; ++i) op[i * 16 + colq] = o[i];
    }

    float4 s4 = {0,0,0,0}, q4 = {0,0,0,0};
    if (node < NN) {
#pragma unroll
        for (int i = 0; i < 4; ++i) {
            s4.x += o[i].x; s4.y += o[i].y; s4.z += o[i].z; s4.w += o[i].w;
            q4.x = fmaf(o[i].x, o[i].x, q4.x); q4.y = fmaf(o[i].y, o[i].y, q4.y);
            q4.z = fmaf(o[i].z, o[i].z, q4.z); q4.w = fmaf(o[i].w, o[i].w, q4.w);
        }
    }
    s4.x += __shfl_xor(s4.x, 16); s4.y += __shfl_xor(s4.y, 16);
    s4.z += __shfl_xor(s4.z, 16); s4.w += __shfl_xor(s4.w, 16);
    q4.x += __shfl_xor(q4.x, 16); q4.y += __shfl_xor(q4.y, 16);
    q4.z += __shfl_xor(q4.z, 16); q4.w += __shfl_xor(q4.w, 16);
    s4.x += __shfl_xor(s4.x, 32); s4.y += __shfl_xor(s4.y, 32);
    s4.z += __shfl_xor(s4.z, 32); s4.w += __shfl_xor(s4.w, 32);
    q4.x += __shfl_xor(q4.x, 32); q4.y += __shfl_xor(q4.y, 32);
    q4.z += __shfl_xor(q4.z, 32); q4.w += __shfl_xor(q4.w, 32);
    __syncthreads();   // all waves done with As -> reuse as scratch
    if (lane < 16) {
        float* S = As + wid * 128;
        *(float4*)(S + lane * 8) = s4;
        *(float4*)(S + lane * 8 + 4) = q4;
    }
    __syncthreads();
    if (tid < 64) {
        int cq = tid >> 2, comp = tid & 3;
        float s = 0.f, q = 0.f;
#pragma unroll
        for (int w = 0; w < 4; ++w) {
            s += As[w * 128 + cq * 8 + comp];
            q += As[w * 128 + cq * 8 + 4 + comp];
        }
        float* sl = stats + (blockIdx.x & (NSLOT - 1)) * 128;
        atomicAdd(&sl[tid], s);
        atomicAdd(&sl[64 + tid], q);
    }
}

// ---------------- k_z: z[b,n] = act(h2 row) . W2[:,63] (streaming) ----------
#define ZBLK 2048
__global__ __launch_bounds__(256) void k_z(
        const float* __restrict__ h2, const float* __restrict__ bnstats,
        const float* __restrict__ gamma, const float* __restrict__ beta,
        const float* __restrict__ W2, float* __restrict__ z) {
    __shared__ float stl[128];
    __shared__ float w63[64];
    int tid = threadIdx.x;
    if (tid < 64) {
        float su = 0.f, qu = 0.f;
#pragma unroll
        for (int s = 0; s < NSLOT; ++s) {
            su += bnstats[s * 128 + tid];
            qu += bnstats[s * 128 + 64 + tid];
        }
        const float inv = 1.0f / (float)(NB * NN);
        float mu = su * inv;
        float var = qu * inv - mu * mu;
        float sc = gamma[tid] / sqrtf(var + 1e-5f);
        stl[tid] = sc;
        stl[64 + tid] = fmaf(-mu, sc, beta[tid]);
        w63[tid] = W2[tid * 64 + 63];
    }
    __syncthreads();
    int lane = tid & 63, wid = tid >> 6;
    int c4 = lane & 15;
    float4 sv = ((const float4*)stl)[c4];
    float4 tv = ((const float4*)(stl + 64))[c4];
    float4 w4 = ((const float4*)w63)[c4];
    const int total = NB * NN;   // 256B rows of h2
    for (int base = blockIdx.x * 16; base < total; base += ZBLK * 16) {
        int row = base + wid * 4 + (lane >> 4);
        float s = 0.f;
        if (row < total) {
            float4 v = ((const float4*)h2)[(size_t)row * 16 + c4];
            v.x = fmaxf(fmaf(v.x, sv.x, tv.x), 0.f);
            v.y = fmaxf(fmaf(v.y, sv.y, tv.y), 0.f);
            v.z = fmaxf(fmaf(v.z, sv.z, tv.z), 0.f);
            v.w = fmaxf(fmaf(v.w, sv.w, tv.w), 0.f);
            s = v.x * w4.x + v.y * w4.y + v.z * w4.z + v.w * w4.w;
        }
        s += __shfl_xor(s, 1);
        s += __shfl_xor(s, 2);
        s += __shfl_xor(s, 4);
        s += __shfl_xor(s, 8);
        if ((lane & 15) == 0 && row < total) z[row] = s;
    }
}

// ---------------- k_score: sparse agg of scalar z -> sc (wave per node) -----
__global__ __launch_bounds__(256) void k_score(
        const float* __restrict__ z, const float* __restrict__ b2,
        const int* __restrict__ rowptr, const int* __restrict__ csr_col,
        const float* __restrict__ csr_nv, const float* __restrict__ dinv,
        float* __restrict__ sc) {
    int tid = threadIdx.x;
    int wid = tid >> 6, lane = tid & 63;
    int g = blockIdx.x & 7;
    int nd = (blockIdx.x >> 3) * 4 + wid;   // 1250*4 = 5000 exactly
    if (nd >= NN) return;                   // no barriers below
    const float4* __restrict__ z4 = (const float4*)z + (size_t)g * NN;
    int p0 = rowptr[nd], p1 = rowptr[nd + 1];
    float4 a = {0.f, 0.f, 0.f, 0.f};
    for (int e = p0 + lane; e < p1; e += 64) {
        int col = csr_col[e];
        float nv = csr_nv[e];        // pad entries have nv=0, col=self: safe
        float4 zv = z4[col];
        fma4(a, nv, zv);
    }
#pragma unroll
    for (int off = 1; off < 64; off <<= 1) {
        a.x += __shfl_xor(a.x, off);
        a.y += __shfl_xor(a.y, off);
        a.z += __shfl_xor(a.z, off);
        a.w += __shfl_xor(a.w, off);
    }
    if (lane == 0) {
        float d = dinv[nd]; d *= d;
        float4 zs = z4[nd];
        float bb = b2[63];
        float4 o;
        o.x = fmaxf(fmaf(d, zs.x, a.x) + bb, 0.f);
        o.y = fmaxf(fmaf(d, zs.y, a.y) + bb, 0.f);
        o.z = fmaxf(fmaf(d, zs.z, a.z) + bb, 0.f);
        o.w = fmaxf(fmaf(d, zs.w, a.w) + bb, 0.f);
        ((float4*)sc)[(size_t)g * NN + nd] = o;
    }
}

// ---------------- sort-pool (blocks 0..31) + bnfin (block 32) ----------------
__global__ __launch_bounds__(1024) void k_toppool(const float* __restrict__ sc, int* order,
        const float* __restrict__ stats,
        const float* __restrict__ g0, const float* __restrict__ be0,
        const float* __restrict__ g1, const float* __restrict__ be1,
        float* __restrict__ st) {
    __shared__ unsigned long long wbest[16];
    __shared__ unsigned long long winner;
    int tid = threadIdx.x;
    if (blockIdx.x == NB) {
        if (tid < 128) {
            int c = tid & 63, layer = tid >> 6;
            const float* sb = stats + layer * NSLOT * 128;
            float su = 0.f, qu = 0.f;
#pragma unroll
            for (int s = 0; s < NSLOT; ++s) {
                su += sb[s * 128 + c];
                qu += sb[s * 128 + 64 + c];
            }
            const float inv = 1.0f / (float)(NB * NN);
            float mu = su * inv;
            float var = qu * inv - mu * mu;
            float g = layer ? g1[c] : g0[c];
            float be = layer ? be1[c] : be0[c];
            float scv = g / sqrtf(var + 1e-5f);
            st[layer * 128 + c] = scv;
            st[layer * 128 + 64 + c] = fmaf(-mu, scv, be);
        }
        return;
    }
    int b = blockIdx.x;
    int g = b >> 2, bi = b & 3;
    int lane = tid & 63, wid = tid >> 6;
    unsigned long long key[5];
#pragma unroll
    for (int j = 0; j < 5; ++j) {
        int n = tid + j * 1024;
        unsigned long long k = 0;
        if (n < NN) {
            float v = sc[((size_t)g * NN + n) * GB + bi];   // already relu'd
            k = ((unsigned long long)__float_as_uint(v) << 32) | (unsigned int)(NN - n);
        }
        key[j] = k;
    }
    for (int k = 0; k < KPOOL; ++k) {
        unsigned long long best = key[0];
#pragma unroll
        for (int j = 1; j < 5; ++j) best = (key[j] > best) ? key[j] : best;
#pragma unroll
        for (int off = 1; off < 64; off <<= 1) {
            unsigned long long o = __shfl_xor(best, off);
            best = (o > best) ? o : best;
        }
        if (lane == 0) wbest[wid] = best;
        __syncthreads();
        if (tid == 0) {
            unsigned long long w = wbest[0];
#pragma unroll
            for (int i = 1; i < 16; ++i) w = (wbest[i] > w) ? wbest[i] : w;
            winner = w;
            order[b * KPOOL + k] = NN - (int)(w & 0xFFFFFFFFu);
        }
        __syncthreads();
        int n = NN - (int)(winner & 0xFFFFFFFFu);
        if ((n & 1023) == tid) key[n >> 10] = 0;   // remove winner (owner thread)
    }
}

// ---------------- gather selected nodes into flat (B, 6241) ----------------
// Aggregates the h3 row for this (b,node) from act(h2) (only 960 pairs — R30),
// then the 64x64 GEMM from LDS.
__global__ void k_gather(const float* __restrict__ xt, const float* __restrict__ h1,
                         const float* __restrict__ h2,
                         const float* __restrict__ W2, const float* __restrict__ b2,
                         const float* __restrict__ st, const float* __restrict__ age,
                         const int* __restrict__ rowptr, const int* __restrict__ csr_col,
                         const float* __restrict__ csr_nv, const float* __restrict__ dinv,
                         const int* __restrict__ order, float* __restrict__ flat) {
    __shared__ float aggP[4][64];
    __shared__ float aggRow[64];
    int bk = blockIdx.x;
    int b = bk / KPOOL, k = bk % KPOOL;
    int n = order[bk];
    int g = b >> 2, bi = b & 3;
    size_t node = (size_t)g * NN + n;
    int tid = threadIdx.x;
    // ---- phase 1: 4-way edge-split aggregation of act(h2) row ----
    {
        int ep = tid >> 6, c = tid & 63;
        float sc1 = st[128 + c], sh1 = st[192 + c];
        float a = 0.f;
        if (ep == 0) {
            float d = dinv[n];
            float v = h2[(node * GB + bi) * CH + c];
            a = d * d * fmaxf(fmaf(v, sc1, sh1), 0.f);
        }
        int p0 = rowptr[n], p1 = rowptr[n + 1];
        for (int e = p0 + ep; e < p1; e += 4) {
            int col = csr_col[e];
            float nv = csr_nv[e];    // pad entries nv=0: safe
            float v = h2[(((size_t)g * NN + col) * GB + bi) * CH + c];
            a += nv * fmaxf(fmaf(v, sc1, sh1), 0.f);
        }
        aggP[ep][c] = a;
    }
    __syncthreads();
    if (tid < 64) aggRow[tid] = aggP[0][tid] + aggP[1][tid] + aggP[2][tid] + aggP[3][tid];
    __syncthreads();
    // ---- phase 2: feature assembly ----
    int f = tid;
    float val = 0.f;
    if (f < DIN) {
        val = xt[(((size_t)(b >> 3) * NN + n) * 8 + (b & 7)) * DIN + f];   // G4 layout
    } else if (f < DIN + CH) {
        int c = f - DIN;
        val = fmaxf(fmaf(h1[(node * GB + bi) * CH + c], st[c], st[64 + c]), 0.f);
    } else if (f < DIN + 2 * CH) {
        int c = f - DIN - CH;
        val = fmaxf(fmaf(h2[(node * GB + bi) * CH + c], st[128 + c], st[192 + c]), 0.f);
    } else if (f < FTOT) {
        int c = f - DIN - 2 * CH;
        float s = b2[c];
#pragma unroll 8
        for (int kk = 0; kk < 64; ++kk)
            s = fmaf(aggRow[kk], W2[kk * 64 + c], s);
        val = fmaxf(s, 0.f);
    }
    if (f < FTOT) flat[(size_t)b * FLATW + k * FTOT + f] = val;
    if (bk == 0 && f >= FTOT && f < FTOT + NB)
        flat[(size_t)(f - FTOT) * FLATW + (FLATW - 1)] = age[f - FTOT];
}

// ---------------- MLP head layer 1: hm += flat @ mW0 (k-split, atomics) ----------------
__global__ void k_head1(const float* __restrict__ flat, const float* __restrict__ mW0,
                        float* hm) {
    int tid = threadIdx.x;
    int j4 = (tid & 31) * 4;       // 32 groups * 4 = 128 cols
    int b0 = (tid >> 5) * 4;       // 8 groups * 4 = 32 rows
    int kbase = blockIdx.x * 64;
    float acc[4][4];
#pragma unroll
    for (int i = 0; i < 4; i++)
#pragma unroll
        for (int jj = 0; jj < 4; jj++) acc[i][jj] = 0.f;
    int kend = FLATW - kbase; if (kend > 64) kend = 64;
    for (int kk = 0; kk < kend; ++kk) {
        int k = kbase + kk;
        float4 w = *(const float4*)(mW0 + (size_t)k * NH + j4);
#pragma unroll
        for (int i = 0; i < 4; i++) {
            float fv = flat[(size_t)(b0 + i) * FLATW + k];
            acc[i][0] = fmaf(fv, w.x, acc[i][0]);
            acc[i][1] = fmaf(fv, w.y, acc[i][1]);
            acc[i][2] = fmaf(fv, w.z, acc[i][2]);
            acc[i][3] = fmaf(fv, w.w, acc[i][3]);
        }
    }
#pragma unroll
    for (int i = 0; i < 4; i++)
#pragma unroll
        for (int jj = 0; jj < 4; jj++)
            atomicAdd(&hm[(size_t)(b0 + i) * NH + j4 + jj], acc[i][jj]);
}

// ---------------- head layer 2 + log_softmax (4-way j-split) ----------------
__global__ void k_head2(const float* __restrict__ hm, const float* __restrict__ mb0,
                        const float* __restrict__ mW1, const float* __restrict__ mb1,
                        float* __restrict__ out) {
    __shared__ float part[256];
    __shared__ float vals[64];
    int tid = threadIdx.x;  // 256 = 32b * 2o * 4q
    int q = tid & 3, o = (tid >> 2) & 1, b = tid >> 3;
    float acc = 0.f;
    for (int j = q * 32; j < q * 32 + 32; ++j) {
        float hv = fmaxf(hm[b * NH + j] + mb0[j], 0.f);
        acc = fmaf(hv, mW1[j * 2 + o], acc);
    }
    part[tid] = acc;
    __syncthreads();
    if (tid < 64) {
        int b2 = tid >> 1, o2 = tid & 1;
        int base = (b2 << 3) + (o2 << 2);
        vals[tid] = part[base] + part[base + 1] + part[base + 2] + part[base + 3] + mb1[o2];
    }
    __syncthreads();
    if (tid < 64) {
        int b2 = tid >> 1;
        float v0 = vals[b2 * 2], v1 = vals[b2 * 2 + 1];
        float m = fmaxf(v0, v1);
        float lse = m + logf(expf(v0 - m) + expf(v1 - m));
        out[tid] = vals[tid] - lse;
    }
}

extern "C" void kernel_launch(void* const* d_in, const int* in_sizes, int n_in,
                              void* d_out, int out_size, void* d_ws, size_t ws_size,
                              hipStream_t stream) {
    const float* x    = (const float*)d_in[0];
    const float* age  = (const float*)d_in[1];
    const float* attr = (const float*)d_in[2];
    const float* W0   = (const float*)d_in[3];
    const float* b0   = (const float*)d_in[4];
    const float* W1   = (const float*)d_in[5];
    const float* b1   = (const float*)d_in[6];
    const float* W2   = (const float*)d_in[7];
    const float* b2   = (const float*)d_in[8];
    const float* g0   = (const float*)d_in[9];
    const float* be0  = (const float*)d_in[10];
    const float* g1   = (const float*)d_in[11];
    const float* be1  = (const float*)d_in[12];
    const float* mW0  = (const float*)d_in[13];
    const float* mb0  = (const float*)d_in[14];
    const float* mW1  = (const float*)d_in[15];
    const float* mb1  = (const float*)d_in[16];
    const int* erow   = (const int*)d_in[17];
    const int* ecol   = (const int*)d_in[18];
    float* out = (float*)d_out;

    // workspace layout (floats); all float4-aligned
    float* ws     = (float*)d_ws;
    float* deg    = ws;                                  // 5008
    float* dinv   = deg + 5008;                          // 5008
    int*   counts = (int*)(dinv + 5008);                 // 5008
    int*   rowptr = counts + 5008;                       // 5008
    int*   cursor = rowptr + 5008;                       // 5008
    int*   perm   = cursor + 5008;                       // 5008
    int*   csr_col= perm + 5008;                         // NEPAD
    float* csr_nv = (float*)(csr_col + NEPAD);           // NEPAD
    float* stats  = csr_nv + NEPAD;                      // 2*32*128 = 8192
    float* st     = stats + 2 * NSLOT * 128;             // 256 (s0,t0,s1,t1)
    float* sc     = st + 256;                            // NG*NN*4 = 160000 (scores)
    int*   order  = (int*)(sc + NB * NN);                // 960
    float* flat   = (float*)(order + 960);               // 32*6241
    float* hm     = flat + (size_t)NB * FLATW;           // 4096
    float* xt     = hm + 4096;                           // (G4,N,8,16)
    float* h1     = xt + (size_t)NB * NN * DIN;          // (G8,N,4,64) each
    float* h2     = h1 + (size_t)NB * NN * CH;
    float* z      = h2 + (size_t)NB * NN * CH;           // NG*NN*4 = 160000

    // graph build: scan+sort+transpose share one dispatch (concurrent roles)
    k_init<<<32, 256, 0, stream>>>(deg, counts, stats, hm, perm);
    k_edges<<<NEB, 256, 0, stream>>>(attr, erow, deg, counts);
    k_phase1<<<2 + (NB * NN + 1023) / 1024, 1024, 0, stream>>>(counts, deg, rowptr, cursor, dinv, perm, x, xt);
    k_build<<<(NE + NN + 1023) / 1024, 1024, 0, stream>>>(erow, ecol, attr, dinv, counts, rowptr, cursor, csr_col, csr_nv);

    // conv0 (G4 wide rows, half the iterations) + conv1 (G8, proven floor);
    // conv2 replaced by z/score/gather-agg (R30)
    k_l16<<<NCHUNK * 4, 256, 0, stream>>>(xt, W0, b0, rowptr, csr_col, csr_nv, dinv, perm, h1, stats);
    k_l64<<<NCHUNK * NG, 256, 0, stream>>>(h1, stats, g0, be0, W1, b1, rowptr, csr_col, csr_nv, dinv, perm, h2, stats + NSLOT * 128);
    k_z<<<ZBLK, 256, 0, stream>>>(h2, stats + NSLOT * 128, g1, be1, W2, z);
    k_score<<<(NN / 4) * NG, 256, 0, stream>>>(z, b2, rowptr, csr_col, csr_nv, dinv, sc);

    // sort-pool (+fused bnfin) + gather (inline agg + deferred GEMM) + head
    k_toppool<<<NB + 1, 1024, 0, stream>>>(sc, order, stats, g0, be0, g1, be1, st);
    k_gather<<<NB * KPOOL, 256, 0, stream>>>(xt, h1, h2, W2, b2, st, age, rowptr, csr_col, csr_nv, dinv, order, flat);
    k_head1<<<(FLATW + 63) / 64, 256, 0, stream>>>(flat, mW0, hm);
    k_head2<<<1, 256, 0, stream>>>(hm, mb0, mW1, mb1, out);
}

// Round 12
// 317.198 us; speedup vs baseline: 1.0039x; 1.0039x over previous
//
#include <hip/hip_runtime.h>
#include <math.h>

// Problem constants (from reference setup_inputs)
#define NN    5000      // nodes
#define NE    80000     // edges
#define NB    32        // batch
#define DIN   16        // input feat
#define CH    64        // conv channels
#define KPOOL 30
#define FTOT  208      // 16 + 3*64
#define FLATW 6241     // KPOOL*FTOT + 1
#define NH    128      // MLP hidden
#define NG    8        // batch groups for CIN64 layer (one per XCD)
#define GB    4        // batches per group (h1/h2 layout)
#define NPB   16       // nodes per block (4 per wave)
#define NCHUNK 313     // node chunks (blocks per group)
#define NPAD  5008     // perm array size
#define NEPAD (NE + 4 * NN)   // CSR rows padded to multiple of 4
#define NSLOT 32       // stats atomic-spread slots

// Journal: R19 ordering / R20+R24 occupancy: dead. R21 CSR rotate: neutral.
// R22 act-hoist: -43% VALU -> -5% dur. R26 serial-merge: 354 -> 348.6.
// R27/28 batch-half: pass-doubling loses (time ~ # gather iterations).
// R29 wide CIN64 rows: VGPR cliff + L2 thrash. CIN64 floor = G8/1KB @ ~71us.
// R30 conv2 killed algebraically: 348.6 -> 316.5. R31 G4 layer-0: NEUTRAL
// (l16 was not the assumed 60-70us hog; kept anyway). R32 (this): the
// ~248us non-l64 pool has ONE structurally-bad critical path: k_toppool's
// 30 rounds x 2 block barriers (~60 syncs, ~20-40us). Rewrite: phase A =
// per-wave top-30 (30 butterfly rounds, ZERO barriers, unique keys ->
// equality = owner removal); ONE barrier; phase B = wave 0 merges 480
// candidates (8 regs/lane, 30 butterfly rounds) emitting descending order.
// Bit-identical total order (same packed keys).

// ---------------- setup kernels ----------------

__global__ void k_init(float* deg, int* counts, float* stats, float* hm, int* perm) {
    int i = blockIdx.x * 256 + threadIdx.x;
    if (i < NN) { deg[i] = 1.0f; counts[i] = 0; }   // deg starts at self-loop value 1
    if (i < 2 * NSLOT * 128) stats[i] = 0.0f;       // [2 layers][32 slots][128]
    if (i < 4096) hm[i] = 0.0f;
    if (i >= NN && i < NPAD) perm[i] = NN;          // tail -> invalid marker
}

#define NEB 313
__global__ void k_edges(const float* __restrict__ attr, const int* __restrict__ erow,
                        float* deg, int* counts) {
    int e = blockIdx.x * 256 + threadIdx.x;
    if (e < NE) {
        int r = erow[e];
        atomicAdd(&deg[r], attr[e]);
        atomicAdd(&counts[r], 1);
    }
}

// merged concurrent phase: block 0 = prefix scan, block 1 = counting sort,
// blocks 2.. = x transpose to (G4,N,8,16) (serial roles hide under transpose).
__global__ __launch_bounds__(1024) void k_phase1(
        const int* __restrict__ counts, const float* __restrict__ deg,
        int* rowptr, int* cursor, float* dinv, int* perm,
        const float* __restrict__ x, float* __restrict__ xt) {
    __shared__ int wsum[16], woff[16];
    __shared__ int carry_sh;
    __shared__ int hist[256];
    int t = threadIdx.x;
    if (blockIdx.x >= 2) {
        int idx = (blockIdx.x - 2) * 1024 + t;
        if (idx >= NB * NN) return;
        int b = idx / NN, n = idx % NN;
        int g4 = b >> 3, bi8 = b & 7;
        const float4* src = (const float4*)(x + (size_t)idx * DIN);
        float4* dst = (float4*)(xt + (((size_t)g4 * NN + n) * 8 + bi8) * DIN);
        dst[0] = src[0]; dst[1] = src[1]; dst[2] = src[2]; dst[3] = src[3];
        return;
    }
    if (blockIdx.x == 0) {
        int lane = t & 63, wid = t >> 6;
        if (t == 0) carry_sh = 0;
        __syncthreads();
        for (int base = 0; base < NN; base += 1024) {
            int carry = carry_sh;
            int i = base + t;
            int v = 0;
            if (i < NN) {
                v = (counts[i] + 3) & ~3;
                dinv[i] = 1.0f / sqrtf(deg[i]);   // deg >= 1 always
            }
            int s = v;
#pragma unroll
            for (int off = 1; off < 64; off <<= 1) {
                int o = __shfl_up(s, off);
                if (lane >= off) s += o;
            }
            if (lane == 63) wsum[wid] = s;
            __syncthreads();
            if (t < 16) {
                int w = wsum[t];
#pragma unroll
                for (int off = 1; off < 16; off <<= 1) {
                    int o = __shfl_up(w, off);
                    if (t >= off) w += o;
                }
                woff[t] = w;
            }
            __syncthreads();
            int inc = s + (wid > 0 ? woff[wid - 1] : 0) + carry;
            if (i < NN) {
                rowptr[i + 1] = inc;
                cursor[i] = inc - v;
            }
            if (t == 1023) carry_sh = carry + woff[15];
            __syncthreads();
        }
        if (t == 0) rowptr[0] = 0;
    } else {
        if (t < 256) hist[t] = 0;
        __syncthreads();
        for (int i = t; i < NN; i += 1024) {
            int b = 255 - min(((counts[i] + 3) & ~3) >> 2, 255);
            atomicAdd(&hist[b], 1);
        }
        __syncthreads();
        int mycnt = (t < 256) ? hist[t] : 0;
        for (int off = 1; off < 256; off <<= 1) {
            int v = (t < 256 && t >= off) ? hist[t - off] : 0;
            __syncthreads();
            if (t < 256) hist[t] += v;
            __syncthreads();
        }
        if (t < 256) hist[t] -= mycnt;
        __syncthreads();
        for (int i = t; i < NN; i += 1024) {
            int b = 255 - min(((counts[i] + 3) & ~3) >> 2, 255);
            int pos = atomicAdd(&hist[b], 1);
            perm[pos] = i;
        }
    }
}

__global__ __launch_bounds__(1024) void k_build(
        const int* __restrict__ erow, const int* __restrict__ ecol,
        const float* __restrict__ attr, const float* __restrict__ dinv,
        const int* __restrict__ counts, const int* __restrict__ rowptr,
        int* cursor, int* csr_col, float* csr_nv) {
    int t = blockIdx.x * 1024 + threadIdx.x;
    if (t < NE) {
        int r = erow[t], c = ecol[t];
        int pos = atomicAdd(&cursor[r], 1);
        csr_col[pos] = c;
        csr_nv[pos] = dinv[r] * attr[t] * dinv[c];
    } else if (t - NE < NN) {
        int i = t - NE;
        int cnt = counts[i];
        int pcnt = (cnt + 3) & ~3;
        int base = rowptr[i + 1] - pcnt;
        for (int p = base + cnt; p < base + pcnt; ++p) { csr_col[p] = i; csr_nv[p] = 0.0f; }
    }
}

// ---------------- helpers ----------------
__device__ __forceinline__ float4 actv(float4 v, float4 s, float4 t) {
    v.x = fmaxf(fmaf(v.x, s.x, t.x), 0.f);
    v.y = fmaxf(fmaf(v.y, s.y, t.y), 0.f);
    v.z = fmaxf(fmaf(v.z, s.z, t.z), 0.f);
    v.w = fmaxf(fmaf(v.w, s.w, t.w), 0.f);
    return v;
}
__device__ __forceinline__ void fma4(float4& a, float w, float4 v) {
    a.x = fmaf(w, v.x, a.x); a.y = fmaf(w, v.y, a.y);
    a.z = fmaf(w, v.z, a.z); a.w = fmaf(w, v.w, a.w);
}
__device__ __forceinline__ void fma2(float2& a, float w, float2 v) {
    a.x = fmaf(w, v.x, a.x); a.y = fmaf(w, v.y, a.y);
}

// ---------------- layer 0 (CIN=16, G4): xt (G4,N,8,16) -> h1 (G8,N,4,64) ----
__global__ __launch_bounds__(256) void k_l16(
        const float* __restrict__ in,
        const float* __restrict__ W, const float* __restrict__ bias,
        const int* __restrict__ rowptr, const int* __restrict__ csr_col,
        const float* __restrict__ csr_nv, const float* __restrict__ dinv,
        const int* __restrict__ perm,
        float* __restrict__ out, float* __restrict__ stats) {
    const int ALS = 18;
    __shared__ float As[4 * 32 * ALS];   // 9216 B
    int tid = threadIdx.x;
    int wid = tid >> 6, lane = tid & 63;
    int g4 = blockIdx.x & 3;
    int base = (blockIdx.x >> 2) * NPB + wid * 4;
    float* Aw = As + wid * 32 * ALS;
    const int4 pid = *(const int4*)(perm + base);

    const float2* __restrict__ in2 = (const float2*)in + (size_t)g4 * NN * 64; // row = 64 f2
    int bi8 = lane >> 3, chp = lane & 7;   // (batch-of-8, ch-pair)

#pragma unroll
    for (int pr = 0; pr < 2; ++pr) {
        int id0 = (pr == 0) ? pid.x : pid.z;
        int id1 = (pr == 0) ? pid.y : pid.w;
        bool vn0 = id0 < NN, vn1 = id1 < NN;
        int rc0 = vn0 ? id0 : 0, rc1 = vn1 ? id1 : 0;
        float dd0 = dinv[rc0]; dd0 *= dd0;
        float dd1 = dinv[rc1]; dd1 *= dd1;
        float2 a0 = {0.f, 0.f}, a1 = {0.f, 0.f};
        {
            float2 v0 = in2[(size_t)rc0 * 64 + lane];
            float2 v1 = in2[(size_t)rc1 * 64 + lane];
            if (vn0) { a0.x = dd0 * v0.x; a0.y = dd0 * v0.y; }
            if (vn1) { a1.x = dd1 * v1.x; a1.y = dd1 * v1.y; }
        }
        int p0a = rowptr[rc0], na = vn0 ? (rowptr[rc0 + 1] - p0a) >> 2 : 0;
        int p0b = rowptr[rc1], nbv = vn1 ? (rowptr[rc1 + 1] - p0b) >> 2 : 0;
        int mx = max(na, nbv);
        for (int bb = 0; bb < mx; ++bb) {
            int ea = min(p0a + 4 * bb, NEPAD - 4);
            int eb = min(p0b + 4 * bb, NEPAD - 4);
            bool va = bb < na, vb = bb < nbv;
            int4   ca = *(const int4*)(csr_col + ea);
            float4 wa = *(const float4*)(csr_nv + ea);
            int4   cb = *(const int4*)(csr_col + eb);
            float4 wb = *(const float4*)(csr_nv + eb);
            if (!va) { wa.x = 0.f; wa.y = 0.f; wa.z = 0.f; wa.w = 0.f;
                       ca.x = 0; ca.y = 0; ca.z = 0; ca.w = 0; }   // poisoned tail
            if (!vb) { wb.x = 0.f; wb.y = 0.f; wb.z = 0.f; wb.w = 0.f;
                       cb.x = 0; cb.y = 0; cb.z = 0; cb.w = 0; }
            float2 u0 = in2[(size_t)ca.x * 64 + lane];
            float2 u1 = in2[(size_t)ca.y * 64 + lane];
            float2 u2 = in2[(size_t)ca.z * 64 + lane];
            float2 u3 = in2[(size_t)ca.w * 64 + lane];
            float2 t0 = in2[(size_t)cb.x * 64 + lane];
            float2 t1 = in2[(size_t)cb.y * 64 + lane];
            float2 t2 = in2[(size_t)cb.z * 64 + lane];
            float2 t3 = in2[(size_t)cb.w * 64 + lane];
            fma2(a0, wa.x, u0);
            fma2(a0, wa.y, u1);
            fma2(a0, wa.z, u2);
            fma2(a0, wa.w, u3);
            fma2(a1, wb.x, t0);
            fma2(a1, wb.y, t1);
            fma2(a1, wb.z, t2);
            fma2(a1, wb.w, t3);
        }
        *(float2*)(Aw + ((2 * pr + 0) * 8 + bi8) * ALS + chp * 2) = a0;
        *(float2*)(Aw + ((2 * pr + 1) * 8 + bi8) * ALS + chp * 2) = a1;
    }
    // NO barrier: stage 2 reads only this wave's Aw slice.

    int colq = lane & 15, rowq = lane >> 4;
    int node = (rowq == 0) ? pid.x : (rowq == 1) ? pid.y : (rowq == 2) ? pid.z : pid.w;

    const float4* __restrict__ W4 = (const float4*)W;
    float4 bb4 = ((const float4*)bias)[colq];
    float4 o[8];
#pragma unroll
    for (int i = 0; i < 8; ++i) o[i] = bb4;
#pragma unroll
    for (int k = 0; k < 16; ++k) {
        float4 w4 = W4[k * 16 + colq];
#pragma unroll
        for (int i = 0; i < 8; ++i)
            fma4(o[i], Aw[(rowq * 8 + i) * ALS + k], w4);
    }
    if (node < NN) {
#pragma unroll
        for (int i = 0; i < 8; ++i) {
            int g8 = g4 * 2 + (i >> 2);
            float4* op = (float4*)(out + (((size_t)g8 * NN + node) * 4 + (i & 3)) * 64);
            op[colq] = o[i];
        }
    }

    // stats (layer 0): lane sums its 8 batches; shfl sums over nodes
    float4 s4 = {0,0,0,0}, q4 = {0,0,0,0};
    if (node < NN) {
#pragma unroll
        for (int i = 0; i < 8; ++i) {
            s4.x += o[i].x; s4.y += o[i].y; s4.z += o[i].z; s4.w += o[i].w;
            q4.x = fmaf(o[i].x, o[i].x, q4.x); q4.y = fmaf(o[i].y, o[i].y, q4.y);
            q4.z = fmaf(o[i].z, o[i].z, q4.z); q4.w = fmaf(o[i].w, o[i].w, q4.w);
        }
    }
    s4.x += __shfl_xor(s4.x, 16); s4.y += __shfl_xor(s4.y, 16);
    s4.z += __shfl_xor(s4.z, 16); s4.w += __shfl_xor(s4.w, 16);
    q4.x += __shfl_xor(q4.x, 16); q4.y += __shfl_xor(q4.y, 16);
    q4.z += __shfl_xor(q4.z, 16); q4.w += __shfl_xor(q4.w, 16);
    s4.x += __shfl_xor(s4.x, 32); s4.y += __shfl_xor(s4.y, 32);
    s4.z += __shfl_xor(s4.z, 32); s4.w += __shfl_xor(s4.w, 32);
    q4.x += __shfl_xor(q4.x, 32); q4.y += __shfl_xor(q4.y, 32);
    q4.z += __shfl_xor(q4.z, 32); q4.w += __shfl_xor(q4.w, 32);
    __syncthreads();   // all waves done with As -> reuse as scratch
    if (lane < 16) {
        float* S = As + wid * 128;
        *(float4*)(S + lane * 8) = s4;
        *(float4*)(S + lane * 8 + 4) = q4;
    }
    __syncthreads();
    if (tid < 64) {
        int cq = tid >> 2, comp = tid & 3;
        float s = 0.f, q = 0.f;
#pragma unroll
        for (int w = 0; w < 4; ++w) {
            s += As[w * 128 + cq * 8 + comp];
            q += As[w * 128 + cq * 8 + 4 + comp];
        }
        float* sl = stats + (blockIdx.x & (NSLOT - 1)) * 128;
        atomicAdd(&sl[tid], s);
        atomicAdd(&sl[64 + tid], q);
    }
}

// ---------------- fused CIN64 GCN layer (R0 proven base — at gather roofline)
__global__ __launch_bounds__(256) void k_l64(
        const float* __restrict__ in, const float* __restrict__ bnstats,
        const float* __restrict__ gamma, const float* __restrict__ beta,
        const float* __restrict__ W, const float* __restrict__ bias,
        const int* __restrict__ rowptr, const int* __restrict__ csr_col,
        const float* __restrict__ csr_nv, const float* __restrict__ dinv,
        const int* __restrict__ perm,
        float* __restrict__ out, float* __restrict__ stats) {
    const int ALS = 68;
    __shared__ float As[4 * 16 * ALS];
    __shared__ float stl[128];
    int tid = threadIdx.x;
    int wid = tid >> 6, lane = tid & 63;
    int g = blockIdx.x & 7;                      // XCD round-robin
    int base = (blockIdx.x >> 3) * NPB + wid * 4;
    float* Aw = As + wid * 16 * ALS;
    const int4 pid = *(const int4*)(perm + base);   // 4 node ids (degree-sorted)

    if (tid < 64) {
        float su = 0.f, qu = 0.f;
#pragma unroll
        for (int s = 0; s < NSLOT; ++s) {
            su += bnstats[s * 128 + tid];
            qu += bnstats[s * 128 + 64 + tid];
        }
        const float inv = 1.0f / (float)(NB * NN);
        float mu = su * inv;
        float var = qu * inv - mu * mu;
        float sc = gamma[tid] / sqrtf(var + 1e-5f);
        stl[tid] = sc;
        stl[64 + tid] = fmaf(-mu, sc, beta[tid]);
    }
    __syncthreads();

    const float4* __restrict__ in4 = (const float4*)in + (size_t)g * NN * 64;
    int c4 = lane & 15, bi = lane >> 4;
    float4 sv = ((const float4*)stl)[c4];
    float4 tv = ((const float4*)(stl + 64))[c4];
#pragma unroll
    for (int pr = 0; pr < 2; ++pr) {
        int id0 = (pr == 0) ? pid.x : pid.z;
        int id1 = (pr == 0) ? pid.y : pid.w;
        bool vn0 = id0 < NN, vn1 = id1 < NN;
        int rc0 = vn0 ? id0 : 0, rc1 = vn1 ? id1 : 0;
        float dd0 = dinv[rc0]; dd0 *= dd0;
        float dd1 = dinv[rc1]; dd1 *= dd1;
        float4 a0 = {0.f,0.f,0.f,0.f}, a1 = {0.f,0.f,0.f,0.f};
        {
            float4 v0 = actv(in4[(size_t)rc0 * 64 + lane], sv, tv);
            float4 v1 = actv(in4[(size_t)rc1 * 64 + lane], sv, tv);
            if (vn0) { a0.x = dd0 * v0.x; a0.y = dd0 * v0.y; a0.z = dd0 * v0.z; a0.w = dd0 * v0.w; }
            if (vn1) { a1.x = dd1 * v1.x; a1.y = dd1 * v1.y; a1.z = dd1 * v1.z; a1.w = dd1 * v1.w; }
        }
        int p0a = rowptr[rc0], na = vn0 ? (rowptr[rc0 + 1] - p0a) >> 2 : 0;
        int p0b = rowptr[rc1], nbv = vn1 ? (rowptr[rc1 + 1] - p0b) >> 2 : 0;
        int mx = max(na, nbv);
        for (int bb = 0; bb < mx; ++bb) {
            int ea = min(p0a + 4 * bb, NEPAD - 4);
            int eb = min(p0b + 4 * bb, NEPAD - 4);
            bool va = bb < na, vb = bb < nbv;
            int4   ca = *(const int4*)(csr_col + ea);
            float4 wa = *(const float4*)(csr_nv + ea);
            int4   cb = *(const int4*)(csr_col + eb);
            float4 wb = *(const float4*)(csr_nv + eb);
            if (!va) { wa.x = 0.f; wa.y = 0.f; wa.z = 0.f; wa.w = 0.f;
                       ca.x = 0; ca.y = 0; ca.z = 0; ca.w = 0; }   // poisoned tail
            if (!vb) { wb.x = 0.f; wb.y = 0.f; wb.z = 0.f; wb.w = 0.f;
                       cb.x = 0; cb.y = 0; cb.z = 0; cb.w = 0; }
            float4 u0 = in4[(size_t)ca.x * 64 + lane];
            float4 u1 = in4[(size_t)ca.y * 64 + lane];
            float4 u2 = in4[(size_t)ca.z * 64 + lane];
            float4 u3 = in4[(size_t)ca.w * 64 + lane];
            float4 t0 = in4[(size_t)cb.x * 64 + lane];
            float4 t1 = in4[(size_t)cb.y * 64 + lane];
            float4 t2 = in4[(size_t)cb.z * 64 + lane];
            float4 t3 = in4[(size_t)cb.w * 64 + lane];
            fma4(a0, wa.x, actv(u0, sv, tv));
            fma4(a0, wa.y, actv(u1, sv, tv));
            fma4(a0, wa.z, actv(u2, sv, tv));
            fma4(a0, wa.w, actv(u3, sv, tv));
            fma4(a1, wb.x, actv(t0, sv, tv));
            fma4(a1, wb.y, actv(t1, sv, tv));
            fma4(a1, wb.z, actv(t2, sv, tv));
            fma4(a1, wb.w, actv(t3, sv, tv));
        }
        *(float4*)(Aw + ((pr * 2 + 0) * 4 + bi) * ALS + c4 * 4) = a0;
        *(float4*)(Aw + ((pr * 2 + 1) * 4 + bi) * ALS + c4 * 4) = a1;
    }
    // NO __syncthreads here: stage 2 reads only this wave's Aw slice.

    int colq = lane & 15, rowq = lane >> 4;
    int node = (rowq == 0) ? pid.x : (rowq == 1) ? pid.y : (rowq == 2) ? pid.z : pid.w;

    // ---- stage 2: per-wave GEMM; thread -> (node rowq, colq) ----
    const float4* __restrict__ W4 = (const float4*)W;
    float4 bb = ((const float4*)bias)[colq];
    float4 o[4];
#pragma unroll
    for (int i = 0; i < 4; ++i) o[i] = bb;
#pragma unroll 8
    for (int k = 0; k < 64; ++k) {
        float4 w4 = W4[k * 16 + colq];
#pragma unroll
        for (int i = 0; i < 4; ++i) {
            float a = Aw[(rowq * 4 + i) * ALS + k];
            fma4(o[i], a, w4);
        }
    }
    if (node < NN) {
        float4* __restrict__ op = (float4*)(out + ((size_t)g * NN + node) * 256);
#pragma unroll
        for (int i = 0; i < 4; ++i) op[i * 16 + colq] = o[i];
    }

    float4 s4 = {0,0,0,0}, q4 = {0,0,0,0};
    if (node < NN) {
#pragma unroll
        for (int i = 0; i < 4; ++i) {
            s4.x += o[i].x; s4.y += o[i].y; s4.z += o[i].z; s4.w += o[i].w;
            q4.x = fmaf(o[i].x, o[i].x, q4.x); q4.y = fmaf(o[i].y, o[i].y, q4.y);
            q4.z = fmaf(o[i].z, o[i].z, q4.z); q4.w = fmaf(o[i].w, o[i].w, q4.w);
        }
    }
    s4.x += __shfl_xor(s4.x, 16); s4.y += __shfl_xor(s4.y, 16);
    s4.z += __shfl_xor(s4.z, 16); s4.w += __shfl_xor(s4.w, 16);
    q4.x += __shfl_xor(q4.x, 16); q4.y += __shfl_xor(q4.y, 16);
    q4.z += __shfl_xor(q4.z, 16); q4.w += __shfl_xor(q4.w, 16);
    s4.x += __shfl_xor(s4.x, 32); s4.y += __shfl_xor(s4.y, 32);
    s4.z += __shfl_xor(s4.z, 32); s4.w += __shfl_xor(s4.w, 32);
    q4.x += __shfl_xor(q4.x, 32); q4.y += __shfl_xor(q4.y, 32);
    q4.z += __shfl_xor(q4.z, 32); q4.w += __shfl_xor(q4.w, 32);
    __syncthreads();   // all waves done with As -> reuse as scratch
    if (lane < 16) {
        float* S = As + wid * 128;
        *(float4*)(S + lane * 8) = s4;
        *(float4*)(S + lane * 8 + 4) = q4;
    }
    __syncthreads();
    if (tid < 64) {
        int cq = tid >> 2, comp = tid & 3;
        float s = 0.f, q = 0.f;
#pragma unroll
        for (int w = 0; w < 4; ++w) {
            s += As[w * 128 + cq * 8 + comp];
            q += As[w * 128 + cq * 8 + 4 + comp];
        }
        float* sl = stats + (blockIdx.x & (NSLOT - 1)) * 128;
        atomicAdd(&sl[tid], s);
        atomicAdd(&sl[64 + tid], q);
    }
}

// ---------------- k_z: z[b,n] = act(h2 row) . W2[:,63] (streaming) ----------
#define ZBLK 2048
__global__ __launch_bounds__(256) void k_z(
        const float* __restrict__ h2, const float* __restrict__ bnstats,
        const float* __restrict__ gamma, const float* __restrict__ beta,
        const float* __restrict__ W2, float* __restrict__ z) {
    __shared__ float stl[128];
    __shared__ float w63[64];
    int tid = threadIdx.x;
    if (tid < 64) {
        float su = 0.f, qu = 0.f;
#pragma unroll
        for (int s = 0; s < NSLOT; ++s) {
            su += bnstats[s * 128 + tid];
            qu += bnstats[s * 128 + 64 + tid];
        }
        const float inv = 1.0f / (float)(NB * NN);
        float mu = su * inv;
        float var = qu * inv - mu * mu;
        float sc = gamma[tid] / sqrtf(var + 1e-5f);
        stl[tid] = sc;
        stl[64 + tid] = fmaf(-mu, sc, beta[tid]);
        w63[tid] = W2[tid * 64 + 63];
    }
    __syncthreads();
    int lane = tid & 63, wid = tid >> 6;
    int c4 = lane & 15;
    float4 sv = ((const float4*)stl)[c4];
    float4 tv = ((const float4*)(stl + 64))[c4];
    float4 w4 = ((const float4*)w63)[c4];
    const int total = NB * NN;   // 256B rows of h2
    for (int base = blockIdx.x * 16; base < total; base += ZBLK * 16) {
        int row = base + wid * 4 + (lane >> 4);
        float s = 0.f;
        if (row < total) {
            float4 v = ((const float4*)h2)[(size_t)row * 16 + c4];
            v.x = fmaxf(fmaf(v.x, sv.x, tv.x), 0.f);
            v.y = fmaxf(fmaf(v.y, sv.y, tv.y), 0.f);
            v.z = fmaxf(fmaf(v.z, sv.z, tv.z), 0.f);
            v.w = fmaxf(fmaf(v.w, sv.w, tv.w), 0.f);
            s = v.x * w4.x + v.y * w4.y + v.z * w4.z + v.w * w4.w;
        }
        s += __shfl_xor(s, 1);
        s += __shfl_xor(s, 2);
        s += __shfl_xor(s, 4);
        s += __shfl_xor(s, 8);
        if ((lane & 15) == 0 && row < total) z[row] = s;
    }
}

// ---------------- k_score: sparse agg of scalar z -> sc (wave per node) -----
__global__ __launch_bounds__(256) void k_score(
        const float* __restrict__ z, const float* __restrict__ b2,
        const int* __restrict__ rowptr, const int* __restrict__ csr_col,
        const float* __restrict__ csr_nv, const float* __restrict__ dinv,
        float* __restrict__ sc) {
    int tid = threadIdx.x;
    int wid = tid >> 6, lane = tid & 63;
    int g = blockIdx.x & 7;
    int nd = (blockIdx.x >> 3) * 4 + wid;   // 1250*4 = 5000 exactly
    if (nd >= NN) return;                   // no barriers below
    const float4* __restrict__ z4 = (const float4*)z + (size_t)g * NN;
    int p0 = rowptr[nd], p1 = rowptr[nd + 1];
    float4 a = {0.f, 0.f, 0.f, 0.f};
    for (int e = p0 + lane; e < p1; e += 64) {
        int col = csr_col[e];
        float nv = csr_nv[e];        // pad entries have nv=0, col=self: safe
        float4 zv = z4[col];
        fma4(a, nv, zv);
    }
#pragma unroll
    for (int off = 1; off < 64; off <<= 1) {
        a.x += __shfl_xor(a.x, off);
        a.y += __shfl_xor(a.y, off);
        a.z += __shfl_xor(a.z, off);
        a.w += __shfl_xor(a.w, off);
    }
    if (lane == 0) {
        float d = dinv[nd]; d *= d;
        float4 zs = z4[nd];
        float bb = b2[63];
        float4 o;
        o.x = fmaxf(fmaf(d, zs.x, a.x) + bb, 0.f);
        o.y = fmaxf(fmaf(d, zs.y, a.y) + bb, 0.f);
        o.z = fmaxf(fmaf(d, zs.z, a.z) + bb, 0.f);
        o.w = fmaxf(fmaf(d, zs.w, a.w) + bb, 0.f);
        ((float4*)sc)[(size_t)g * NN + nd] = o;
    }
}

// ---------------- sort-pool (blocks 0..31, barrier-free) + bnfin (block 32) --
// R32: phase A = each wave keeps top-30 of its 320 elements via 30 butterfly
// argmax rounds (keys unique: score bits << 32 | NN-n; equality = owner).
// ONE barrier. Phase B = wave 0 merges the 16x30 candidates (8 regs/lane,
// 30 butterfly rounds), emitting winners in descending order. Total order
// identical to the old 60-barrier version.
__global__ __launch_bounds__(1024) void k_toppool(const float* __restrict__ sc, int* order,
        const float* __restrict__ stats,
        const float* __restrict__ g0, const float* __restrict__ be0,
        const float* __restrict__ g1, const float* __restrict__ be1,
        float* __restrict__ st) {
    __shared__ unsigned long long cand[16 * KPOOL];
    int tid = threadIdx.x;
    if (blockIdx.x == NB) {
        if (tid < 128) {
            int c = tid & 63, layer = tid >> 6;
            const float* sb = stats + layer * NSLOT * 128;
            float su = 0.f, qu = 0.f;
#pragma unroll
            for (int s = 0; s < NSLOT; ++s) {
                su += sb[s * 128 + c];
                qu += sb[s * 128 + 64 + c];
            }
            const float inv = 1.0f / (float)(NB * NN);
            float mu = su * inv;
            float var = qu * inv - mu * mu;
            float g = layer ? g1[c] : g0[c];
            float be = layer ? be1[c] : be0[c];
            float scv = g / sqrtf(var + 1e-5f);
            st[layer * 128 + c] = scv;
            st[layer * 128 + 64 + c] = fmaf(-mu, scv, be);
        }
        return;
    }
    int b = blockIdx.x;
    int g = b >> 2, bi = b & 3;
    int lane = tid & 63, wid = tid >> 6;
    unsigned long long key[5];
#pragma unroll
    for (int j = 0; j < 5; ++j) {
        int n = tid + j * 1024;
        unsigned long long k = 0;
        if (n < NN) {
            float v = sc[((size_t)g * NN + n) * GB + bi];   // already relu'd
            k = ((unsigned long long)__float_as_uint(v) << 32) | (unsigned int)(NN - n);
        }
        key[j] = k;
    }
    // ---- phase A: per-wave top-30 (no barriers; keys unique -> eq = owner) --
    for (int k = 0; k < KPOOL; ++k) {
        unsigned long long best = key[0];
#pragma unroll
        for (int j = 1; j < 5; ++j) best = (key[j] > best) ? key[j] : best;
#pragma unroll
        for (int off = 1; off < 64; off <<= 1) {
            unsigned long long o = __shfl_xor(best, off);
            best = (o > best) ? o : best;
        }
        if (best) {
#pragma unroll
            for (int j = 0; j < 5; ++j) if (key[j] == best) key[j] = 0;
        }
        if (lane == 0) cand[wid * KPOOL + k] = best;
    }
    __syncthreads();
    // ---- phase B: wave 0 merges 480 candidates -> global top-30 in order ----
    if (wid == 0) {
        unsigned long long r[8];
#pragma unroll
        for (int i = 0; i < 8; ++i) {
            int idx = i * 64 + lane;
            r[i] = (idx < 16 * KPOOL) ? cand[idx] : 0;
        }
        for (int k = 0; k < KPOOL; ++k) {
            unsigned long long best = r[0];
#pragma unroll
            for (int i = 1; i < 8; ++i) best = (r[i] > best) ? r[i] : best;
#pragma unroll
            for (int off = 1; off < 64; off <<= 1) {
                unsigned long long o = __shfl_xor(best, off);
                best = (o > best) ? o : best;
            }
            if (best) {
#pragma unroll
                for (int i = 0; i < 8; ++i) if (r[i] == best) r[i] = 0;
            }
            if (lane == 0) order[b * KPOOL + k] = NN - (int)(best & 0xFFFFFFFFu);
        }
    }
}

// ---------------- gather selected nodes into flat (B, 6241) ----------------
__global__ void k_gather(const float* __restrict__ xt, const float* __restrict__ h1,
                         const float* __restrict__ h2,
                         const float* __restrict__ W2, const float* __restrict__ b2,
                         const float* __restrict__ st, const float* __restrict__ age,
                         const int* __restrict__ rowptr, const int* __restrict__ csr_col,
                         const float* __restrict__ csr_nv, const float* __restrict__ dinv,
                         const int* __restrict__ order, float* __restrict__ flat) {
    __shared__ float aggP[4][64];
    __shared__ float aggRow[64];
    int bk = blockIdx.x;
    int b = bk / KPOOL, k = bk % KPOOL;
    int n = order[bk];
    int g = b >> 2, bi = b & 3;
    size_t node = (size_t)g * NN + n;
    int tid = threadIdx.x;
    // ---- phase 1: 4-way edge-split aggregation of act(h2) row ----
    {
        int ep = tid >> 6, c = tid & 63;
        float sc1 = st[128 + c], sh1 = st[192 + c];
        float a = 0.f;
        if (ep == 0) {
            float d = dinv[n];
            float v = h2[(node * GB + bi) * CH + c];
            a = d * d * fmaxf(fmaf(v, sc1, sh1), 0.f);
        }
        int p0 = rowptr[n], p1 = rowptr[n + 1];
        for (int e = p0 + ep; e < p1; e += 4) {
            int col = csr_col[e];
            float nv = csr_nv[e];    // pad entries nv=0: safe
            float v = h2[(((size_t)g * NN + col) * GB + bi) * CH + c];
            a += nv * fmaxf(fmaf(v, sc1, sh1), 0.f);
        }
        aggP[ep][c] = a;
    }
    __syncthreads();
    if (tid < 64) aggRow[tid] = aggP[0][tid] + aggP[1][tid] + aggP[2][tid] + aggP[3][tid];
    __syncthreads();
    // ---- phase 2: feature assembly ----
    int f = tid;
    float val = 0.f;
    if (f < DIN) {
        val = xt[(((size_t)(b >> 3) * NN + n) * 8 + (b & 7)) * DIN + f];   // G4 layout
    } else if (f < DIN + CH) {
        int c = f - DIN;
        val = fmaxf(fmaf(h1[(node * GB + bi) * CH + c], st[c], st[64 + c]), 0.f);
    } else if (f < DIN + 2 * CH) {
        int c = f - DIN - CH;
        val = fmaxf(fmaf(h2[(node * GB + bi) * CH + c], st[128 + c], st[192 + c]), 0.f);
    } else if (f < FTOT) {
        int c = f - DIN - 2 * CH;
        float s = b2[c];
#pragma unroll 8
        for (int kk = 0; kk < 64; ++kk)
            s = fmaf(aggRow[kk], W2[kk * 64 + c], s);
        val = fmaxf(s, 0.f);
    }
    if (f < FTOT) flat[(size_t)b * FLATW + k * FTOT + f] = val;
    if (bk == 0 && f >= FTOT && f < FTOT + NB)
        flat[(size_t)(f - FTOT) * FLATW + (FLATW - 1)] = age[f - FTOT];
}

// ---------------- MLP head layer 1: hm += flat @ mW0 (k-split, atomics) ----------------
__global__ void k_head1(const float* __restrict__ flat, const float* __restrict__ mW0,
                        float* hm) {
    int tid = threadIdx.x;
    int j4 = (tid & 31) * 4;       // 32 groups * 4 = 128 cols
    int b0 = (tid >> 5) * 4;       // 8 groups * 4 = 32 rows
    int kbase = blockIdx.x * 64;
    float acc[4][4];
#pragma unroll
    for (int i = 0; i < 4; i++)
#pragma unroll
        for (int jj = 0; jj < 4; jj++) acc[i][jj] = 0.f;
    int kend = FLATW - kbase; if (kend > 64) kend = 64;
    for (int kk = 0; kk < kend; ++kk) {
        int k = kbase + kk;
        float4 w = *(const float4*)(mW0 + (size_t)k * NH + j4);
#pragma unroll
        for (int i = 0; i < 4; i++) {
            float fv = flat[(size_t)(b0 + i) * FLATW + k];
            acc[i][0] = fmaf(fv, w.x, acc[i][0]);
            acc[i][1] = fmaf(fv, w.y, acc[i][1]);
            acc[i][2] = fmaf(fv, w.z, acc[i][2]);
            acc[i][3] = fmaf(fv, w.w, acc[i][3]);
        }
    }
#pragma unroll
    for (int i = 0; i < 4; i++)
#pragma unroll
        for (int jj = 0; jj < 4; jj++)
            atomicAdd(&hm[(size_t)(b0 + i) * NH + j4 + jj], acc[i][jj]);
}

// ---------------- head layer 2 + log_softmax (4-way j-split) ----------------
__global__ void k_head2(const float* __restrict__ hm, const float* __restrict__ mb0,
                        const float* __restrict__ mW1, const float* __restrict__ mb1,
                        float* __restrict__ out) {
    __shared__ float part[256];
    __shared__ float vals[64];
    int tid = threadIdx.x;  // 256 = 32b * 2o * 4q
    int q = tid & 3, o = (tid >> 2) & 1, b = tid >> 3;
    float acc = 0.f;
    for (int j = q * 32; j < q * 32 + 32; ++j) {
        float hv = fmaxf(hm[b * NH + j] + mb0[j], 0.f);
        acc = fmaf(hv, mW1[j * 2 + o], acc);
    }
    part[tid] = acc;
    __syncthreads();
    if (tid < 64) {
        int b2 = tid >> 1, o2 = tid & 1;
        int base = (b2 << 3) + (o2 << 2);
        vals[tid] = part[base] + part[base + 1] + part[base + 2] + part[base + 3] + mb1[o2];
    }
    __syncthreads();
    if (tid < 64) {
        int b2 = tid >> 1;
        float v0 = vals[b2 * 2], v1 = vals[b2 * 2 + 1];
        float m = fmaxf(v0, v1);
        float lse = m + logf(expf(v0 - m) + expf(v1 - m));
        out[tid] = vals[tid] - lse;
    }
}

extern "C" void kernel_launch(void* const* d_in, const int* in_sizes, int n_in,
                              void* d_out, int out_size, void* d_ws, size_t ws_size,
                              hipStream_t stream) {
    const float* x    = (const float*)d_in[0];
    const float* age  = (const float*)d_in[1];
    const float* attr = (const float*)d_in[2];
    const float* W0   = (const float*)d_in[3];
    const float* b0   = (const float*)d_in[4];
    const float* W1   = (const float*)d_in[5];
    const float* b1   = (const float*)d_in[6];
    const float* W2   = (const float*)d_in[7];
    const float* b2   = (const float*)d_in[8];
    const float* g0   = (const float*)d_in[9];
    const float* be0  = (const float*)d_in[10];
    const float* g1   = (const float*)d_in[11];
    const float* be1  = (const float*)d_in[12];
    const float* mW0  = (const float*)d_in[13];
    const float* mb0  = (const float*)d_in[14];
    const float* mW1  = (const float*)d_in[15];
    const float* mb1  = (const float*)d_in[16];
    const int* erow   = (const int*)d_in[17];
    const int* ecol   = (const int*)d_in[18];
    float* out = (float*)d_out;

    // workspace layout (floats); all float4-aligned
    float* ws     = (float*)d_ws;
    float* deg    = ws;                                  // 5008
    float* dinv   = deg + 5008;                          // 5008
    int*   counts = (int*)(dinv + 5008);                 // 5008
    int*   rowptr = counts + 5008;                       // 5008
    int*   cursor = rowptr + 5008;                       // 5008
    int*   perm   = cursor + 5008;                       // 5008
    int*   csr_col= perm + 5008;                         // NEPAD
    float* csr_nv = (float*)(csr_col + NEPAD);           // NEPAD
    float* stats  = csr_nv + NEPAD;                      // 2*32*128 = 8192
    float* st     = stats + 2 * NSLOT * 128;             // 256 (s0,t0,s1,t1)
    float* sc     = st + 256;                            // NG*NN*4 = 160000 (scores)
    int*   order  = (int*)(sc + NB * NN);                // 960
    float* flat   = (float*)(order + 960);               // 32*6241
    float* hm     = flat + (size_t)NB * FLATW;           // 4096
    float* xt     = hm + 4096;                           // (G4,N,8,16)
    float* h1     = xt + (size_t)NB * NN * DIN;          // (G8,N,4,64) each
    float* h2     = h1 + (size_t)NB * NN * CH;
    float* z      = h2 + (size_t)NB * NN * CH;           // NG*NN*4 = 160000

    // graph build: scan+sort+transpose share one dispatch (concurrent roles)
    k_init<<<32, 256, 0, stream>>>(deg, counts, stats, hm, perm);
    k_edges<<<NEB, 256, 0, stream>>>(attr, erow, deg, counts);
    k_phase1<<<2 + (NB * NN + 1023) / 1024, 1024, 0, stream>>>(counts, deg, rowptr, cursor, dinv, perm, x, xt);
    k_build<<<(NE + NN + 1023) / 1024, 1024, 0, stream>>>(erow, ecol, attr, dinv, counts, rowptr, cursor, csr_col, csr_nv);

    // conv0 (G4) + conv1 (G8, proven floor); conv2 = z/score/gather-agg (R30)
    k_l16<<<NCHUNK * 4, 256, 0, stream>>>(xt, W0, b0, rowptr, csr_col, csr_nv, dinv, perm, h1, stats);
    k_l64<<<NCHUNK * NG, 256, 0, stream>>>(h1, stats, g0, be0, W1, b1, rowptr, csr_col, csr_nv, dinv, perm, h2, stats + NSLOT * 128);
    k_z<<<ZBLK, 256, 0, stream>>>(h2, stats + NSLOT * 128, g1, be1, W2, z);
    k_score<<<(NN / 4) * NG, 256, 0, stream>>>(z, b2, rowptr, csr_col, csr_nv, dinv, sc);

    // sort-pool (barrier-free, +fused bnfin) + gather (inline agg) + head
    k_toppool<<<NB + 1, 1024, 0, stream>>>(sc, order, stats, g0, be0, g1, be1, st);
    k_gather<<<NB * KPOOL, 256, 0, stream>>>(xt, h1, h2, W2, b2, st, age, rowptr, csr_col, csr_nv, dinv, order, flat);
    k_head1<<<(FLATW + 63) / 64, 256, 0, stream>>>(flat, mW0, hm);
    k_head2<<<1, 256, 0, stream>>>(hm, mb0, mW1, mb1, out);
}

// Round 13
// 305.758 us; speedup vs baseline: 1.0415x; 1.0374x over previous
//
#include <hip/hip_runtime.h>
#include <math.h>

// Problem constants (from reference setup_inputs)
#define NN    5000      // nodes
#define NE    80000     // edges
#define NB    32        // batch
#define DIN   16        // input feat
#define CH    64        // conv channels
#define KPOOL 30
#define FTOT  208      // 16 + 3*64
#define FLATW 6241     // KPOOL*FTOT + 1
#define NH    128      // MLP hidden
#define NG    8        // batch groups for CIN64 layer (one per XCD)
#define GB    4        // batches per group (h1/h2 layout)
#define NPB   16       // nodes per block (4 per wave)
#define NCHUNK 313     // node chunks (blocks per group)
#define NPAD  5008     // perm array size
#define NEPAD (NE + 4 * NN)   // CSR rows padded to multiple of 4
#define NSLOT 32       // stats atomic-spread slots

// Journal: R19 ordering / R20+R24 occupancy: dead. R21 CSR rotate: neutral.
// R22 act-hoist: -43% VALU -> -5% dur. R26 serial-merge: 354 -> 348.6.
// R27/28 batch-half: pass-doubling loses. R29 wide rows: VGPR cliff.
// R30 conv2 killed algebraically: 348.6 -> 316.5. R31 G4 layer-0: neutral.
// R32 barrier-free toppool: neutral. R33 (this): model refit — all evidence
// (R8 same-instr half-bytes -13%; R9 same-instr wide rows no-gain; R22 VALU
// ablation -5%) fits VMEM-INSTRUCTION-RATE bound (~16cy/wave64-load at the
// CU L2 port, width/hit-rate-independent). k_l64 stage-2 re-fetches the same
// 16KB W from global 64x per wave (1/3 of its VMEM instrs, never ablated).
// Cache W in LDS (one coalesced block-load; ds_read skips the port) in
// l64 (+16KB LDS -> 34.3KB, 4 blk/CU = 16 waves >= today's 14.4), l16 (4KB),
// and k_gather's deferred GEMM (16KB).

// ---------------- setup kernels ----------------

__global__ void k_init(float* deg, int* counts, float* stats, float* hm, int* perm) {
    int i = blockIdx.x * 256 + threadIdx.x;
    if (i < NN) { deg[i] = 1.0f; counts[i] = 0; }   // deg starts at self-loop value 1
    if (i < 2 * NSLOT * 128) stats[i] = 0.0f;       // [2 layers][32 slots][128]
    if (i < 4096) hm[i] = 0.0f;
    if (i >= NN && i < NPAD) perm[i] = NN;          // tail -> invalid marker
}

#define NEB 313
__global__ void k_edges(const float* __restrict__ attr, const int* __restrict__ erow,
                        float* deg, int* counts) {
    int e = blockIdx.x * 256 + threadIdx.x;
    if (e < NE) {
        int r = erow[e];
        atomicAdd(&deg[r], attr[e]);
        atomicAdd(&counts[r], 1);
    }
}

// merged concurrent phase: block 0 = prefix scan, block 1 = counting sort,
// blocks 2.. = x transpose to (G4,N,8,16) (serial roles hide under transpose).
__global__ __launch_bounds__(1024) void k_phase1(
        const int* __restrict__ counts, const float* __restrict__ deg,
        int* rowptr, int* cursor, float* dinv, int* perm,
        const float* __restrict__ x, float* __restrict__ xt) {
    __shared__ int wsum[16], woff[16];
    __shared__ int carry_sh;
    __shared__ int hist[256];
    int t = threadIdx.x;
    if (blockIdx.x >= 2) {
        int idx = (blockIdx.x - 2) * 1024 + t;
        if (idx >= NB * NN) return;
        int b = idx / NN, n = idx % NN;
        int g4 = b >> 3, bi8 = b & 7;
        const float4* src = (const float4*)(x + (size_t)idx * DIN);
        float4* dst = (float4*)(xt + (((size_t)g4 * NN + n) * 8 + bi8) * DIN);
        dst[0] = src[0]; dst[1] = src[1]; dst[2] = src[2]; dst[3] = src[3];
        return;
    }
    if (blockIdx.x == 0) {
        int lane = t & 63, wid = t >> 6;
        if (t == 0) carry_sh = 0;
        __syncthreads();
        for (int base = 0; base < NN; base += 1024) {
            int carry = carry_sh;
            int i = base + t;
            int v = 0;
            if (i < NN) {
                v = (counts[i] + 3) & ~3;
                dinv[i] = 1.0f / sqrtf(deg[i]);   // deg >= 1 always
            }
            int s = v;
#pragma unroll
            for (int off = 1; off < 64; off <<= 1) {
                int o = __shfl_up(s, off);
                if (lane >= off) s += o;
            }
            if (lane == 63) wsum[wid] = s;
            __syncthreads();
            if (t < 16) {
                int w = wsum[t];
#pragma unroll
                for (int off = 1; off < 16; off <<= 1) {
                    int o = __shfl_up(w, off);
                    if (t >= off) w += o;
                }
                woff[t] = w;
            }
            __syncthreads();
            int inc = s + (wid > 0 ? woff[wid - 1] : 0) + carry;
            if (i < NN) {
                rowptr[i + 1] = inc;
                cursor[i] = inc - v;
            }
            if (t == 1023) carry_sh = carry + woff[15];
            __syncthreads();
        }
        if (t == 0) rowptr[0] = 0;
    } else {
        if (t < 256) hist[t] = 0;
        __syncthreads();
        for (int i = t; i < NN; i += 1024) {
            int b = 255 - min(((counts[i] + 3) & ~3) >> 2, 255);
            atomicAdd(&hist[b], 1);
        }
        __syncthreads();
        int mycnt = (t < 256) ? hist[t] : 0;
        for (int off = 1; off < 256; off <<= 1) {
            int v = (t < 256 && t >= off) ? hist[t - off] : 0;
            __syncthreads();
            if (t < 256) hist[t] += v;
            __syncthreads();
        }
        if (t < 256) hist[t] -= mycnt;
        __syncthreads();
        for (int i = t; i < NN; i += 1024) {
            int b = 255 - min(((counts[i] + 3) & ~3) >> 2, 255);
            int pos = atomicAdd(&hist[b], 1);
            perm[pos] = i;
        }
    }
}

__global__ __launch_bounds__(1024) void k_build(
        const int* __restrict__ erow, const int* __restrict__ ecol,
        const float* __restrict__ attr, const float* __restrict__ dinv,
        const int* __restrict__ counts, const int* __restrict__ rowptr,
        int* cursor, int* csr_col, float* csr_nv) {
    int t = blockIdx.x * 1024 + threadIdx.x;
    if (t < NE) {
        int r = erow[t], c = ecol[t];
        int pos = atomicAdd(&cursor[r], 1);
        csr_col[pos] = c;
        csr_nv[pos] = dinv[r] * attr[t] * dinv[c];
    } else if (t - NE < NN) {
        int i = t - NE;
        int cnt = counts[i];
        int pcnt = (cnt + 3) & ~3;
        int base = rowptr[i + 1] - pcnt;
        for (int p = base + cnt; p < base + pcnt; ++p) { csr_col[p] = i; csr_nv[p] = 0.0f; }
    }
}

// ---------------- helpers ----------------
__device__ __forceinline__ float4 actv(float4 v, float4 s, float4 t) {
    v.x = fmaxf(fmaf(v.x, s.x, t.x), 0.f);
    v.y = fmaxf(fmaf(v.y, s.y, t.y), 0.f);
    v.z = fmaxf(fmaf(v.z, s.z, t.z), 0.f);
    v.w = fmaxf(fmaf(v.w, s.w, t.w), 0.f);
    return v;
}
__device__ __forceinline__ void fma4(float4& a, float w, float4 v) {
    a.x = fmaf(w, v.x, a.x); a.y = fmaf(w, v.y, a.y);
    a.z = fmaf(w, v.z, a.z); a.w = fmaf(w, v.w, a.w);
}
__device__ __forceinline__ void fma2(float2& a, float w, float2 v) {
    a.x = fmaf(w, v.x, a.x); a.y = fmaf(w, v.y, a.y);
}

// ---------------- layer 0 (CIN=16, G4): xt (G4,N,8,16) -> h1 (G8,N,4,64) ----
__global__ __launch_bounds__(256) void k_l16(
        const float* __restrict__ in,
        const float* __restrict__ W, const float* __restrict__ bias,
        const int* __restrict__ rowptr, const int* __restrict__ csr_col,
        const float* __restrict__ csr_nv, const float* __restrict__ dinv,
        const int* __restrict__ perm,
        float* __restrict__ out, float* __restrict__ stats) {
    const int ALS = 18;
    __shared__ float As[4 * 32 * ALS];   // 9216 B
    __shared__ float Wl[16 * 64];        // R33: W cached in LDS (4 KB)
    int tid = threadIdx.x;
    int wid = tid >> 6, lane = tid & 63;
    int g4 = blockIdx.x & 3;
    int base = (blockIdx.x >> 2) * NPB + wid * 4;
    float* Aw = As + wid * 32 * ALS;
    const int4 pid = *(const int4*)(perm + base);

    ((float4*)Wl)[tid] = ((const float4*)W)[tid];   // 256 float4 = whole W
    __syncthreads();

    const float2* __restrict__ in2 = (const float2*)in + (size_t)g4 * NN * 64; // row = 64 f2
    int bi8 = lane >> 3, chp = lane & 7;   // (batch-of-8, ch-pair)

#pragma unroll
    for (int pr = 0; pr < 2; ++pr) {
        int id0 = (pr == 0) ? pid.x : pid.z;
        int id1 = (pr == 0) ? pid.y : pid.w;
        bool vn0 = id0 < NN, vn1 = id1 < NN;
        int rc0 = vn0 ? id0 : 0, rc1 = vn1 ? id1 : 0;
        float dd0 = dinv[rc0]; dd0 *= dd0;
        float dd1 = dinv[rc1]; dd1 *= dd1;
        float2 a0 = {0.f, 0.f}, a1 = {0.f, 0.f};
        {
            float2 v0 = in2[(size_t)rc0 * 64 + lane];
            float2 v1 = in2[(size_t)rc1 * 64 + lane];
            if (vn0) { a0.x = dd0 * v0.x; a0.y = dd0 * v0.y; }
            if (vn1) { a1.x = dd1 * v1.x; a1.y = dd1 * v1.y; }
        }
        int p0a = rowptr[rc0], na = vn0 ? (rowptr[rc0 + 1] - p0a) >> 2 : 0;
        int p0b = rowptr[rc1], nbv = vn1 ? (rowptr[rc1 + 1] - p0b) >> 2 : 0;
        int mx = max(na, nbv);
        for (int bb = 0; bb < mx; ++bb) {
            int ea = min(p0a + 4 * bb, NEPAD - 4);
            int eb = min(p0b + 4 * bb, NEPAD - 4);
            bool va = bb < na, vb = bb < nbv;
            int4   ca = *(const int4*)(csr_col + ea);
            float4 wa = *(const float4*)(csr_nv + ea);
            int4   cb = *(const int4*)(csr_col + eb);
            float4 wb = *(const float4*)(csr_nv + eb);
            if (!va) { wa.x = 0.f; wa.y = 0.f; wa.z = 0.f; wa.w = 0.f;
                       ca.x = 0; ca.y = 0; ca.z = 0; ca.w = 0; }   // poisoned tail
            if (!vb) { wb.x = 0.f; wb.y = 0.f; wb.z = 0.f; wb.w = 0.f;
                       cb.x = 0; cb.y = 0; cb.z = 0; cb.w = 0; }
            float2 u0 = in2[(size_t)ca.x * 64 + lane];
            float2 u1 = in2[(size_t)ca.y * 64 + lane];
            float2 u2 = in2[(size_t)ca.z * 64 + lane];
            float2 u3 = in2[(size_t)ca.w * 64 + lane];
            float2 t0 = in2[(size_t)cb.x * 64 + lane];
            float2 t1 = in2[(size_t)cb.y * 64 + lane];
            float2 t2 = in2[(size_t)cb.z * 64 + lane];
            float2 t3 = in2[(size_t)cb.w * 64 + lane];
            fma2(a0, wa.x, u0);
            fma2(a0, wa.y, u1);
            fma2(a0, wa.z, u2);
            fma2(a0, wa.w, u3);
            fma2(a1, wb.x, t0);
            fma2(a1, wb.y, t1);
            fma2(a1, wb.z, t2);
            fma2(a1, wb.w, t3);
        }
        *(float2*)(Aw + ((2 * pr + 0) * 8 + bi8) * ALS + chp * 2) = a0;
        *(float2*)(Aw + ((2 * pr + 1) * 8 + bi8) * ALS + chp * 2) = a1;
    }
    // NO barrier: stage 2 reads only this wave's Aw slice.

    int colq = lane & 15, rowq = lane >> 4;
    int node = (rowq == 0) ? pid.x : (rowq == 1) ? pid.y : (rowq == 2) ? pid.z : pid.w;

    float4 bb4 = ((const float4*)bias)[colq];
    float4 o[8];
#pragma unroll
    for (int i = 0; i < 8; ++i) o[i] = bb4;
#pragma unroll
    for (int k = 0; k < 16; ++k) {
        float4 w4 = ((const float4*)Wl)[k * 16 + colq];
#pragma unroll
        for (int i = 0; i < 8; ++i)
            fma4(o[i], Aw[(rowq * 8 + i) * ALS + k], w4);
    }
    if (node < NN) {
#pragma unroll
        for (int i = 0; i < 8; ++i) {
            int g8 = g4 * 2 + (i >> 2);
            float4* op = (float4*)(out + (((size_t)g8 * NN + node) * 4 + (i & 3)) * 64);
            op[colq] = o[i];
        }
    }

    // stats (layer 0): lane sums its 8 batches; shfl sums over nodes
    float4 s4 = {0,0,0,0}, q4 = {0,0,0,0};
    if (node < NN) {
#pragma unroll
        for (int i = 0; i < 8; ++i) {
            s4.x += o[i].x; s4.y += o[i].y; s4.z += o[i].z; s4.w += o[i].w;
            q4.x = fmaf(o[i].x, o[i].x, q4.x); q4.y = fmaf(o[i].y, o[i].y, q4.y);
            q4.z = fmaf(o[i].z, o[i].z, q4.z); q4.w = fmaf(o[i].w, o[i].w, q4.w);
        }
    }
    s4.x += __shfl_xor(s4.x, 16); s4.y += __shfl_xor(s4.y, 16);
    s4.z += __shfl_xor(s4.z, 16); s4.w += __shfl_xor(s4.w, 16);
    q4.x += __shfl_xor(q4.x, 16); q4.y += __shfl_xor(q4.y, 16);
    q4.z += __shfl_xor(q4.z, 16); q4.w += __shfl_xor(q4.w, 16);
    s4.x += __shfl_xor(s4.x, 32); s4.y += __shfl_xor(s4.y, 32);
    s4.z += __shfl_xor(s4.z, 32); s4.w += __shfl_xor(s4.w, 32);
    q4.x += __shfl_xor(q4.x, 32); q4.y += __shfl_xor(q4.y, 32);
    q4.z += __shfl_xor(q4.z, 32); q4.w += __shfl_xor(q4.w, 32);
    __syncthreads();   // all waves done with As -> reuse as scratch
    if (lane < 16) {
        float* S = As + wid * 128;
        *(float4*)(S + lane * 8) = s4;
        *(float4*)(S + lane * 8 + 4) = q4;
    }
    __syncthreads();
    if (tid < 64) {
        int cq = tid >> 2, comp = tid & 3;
        float s = 0.f, q = 0.f;
#pragma unroll
        for (int w = 0; w < 4; ++w) {
            s += As[w * 128 + cq * 8 + comp];
            q += As[w * 128 + cq * 8 + 4 + comp];
        }
        float* sl = stats + (blockIdx.x & (NSLOT - 1)) * 128;
        atomicAdd(&sl[tid], s);
        atomicAdd(&sl[64 + tid], q);
    }
}

// ---------------- fused CIN64 GCN layer (gather floor + LDS-cached W) --------
__global__ __launch_bounds__(256) void k_l64(
        const float* __restrict__ in, const float* __restrict__ bnstats,
        const float* __restrict__ gamma, const float* __restrict__ beta,
        const float* __restrict__ W, const float* __restrict__ bias,
        const int* __restrict__ rowptr, const int* __restrict__ csr_col,
        const float* __restrict__ csr_nv, const float* __restrict__ dinv,
        const int* __restrict__ perm,
        float* __restrict__ out, float* __restrict__ stats) {
    const int ALS = 68;
    __shared__ float As[4 * 16 * ALS];
    __shared__ float stl[128];
    __shared__ float Wl[64 * 64];        // R33: W cached in LDS (16 KB)
    int tid = threadIdx.x;
    int wid = tid >> 6, lane = tid & 63;
    int g = blockIdx.x & 7;                      // XCD round-robin
    int base = (blockIdx.x >> 3) * NPB + wid * 4;
    float* Aw = As + wid * 16 * ALS;
    const int4 pid = *(const int4*)(perm + base);   // 4 node ids (degree-sorted)

    {   // W -> LDS: 1024 float4, coalesced, 4 per thread
        float4* d = (float4*)Wl;
        const float4* s = (const float4*)W;
#pragma unroll
        for (int i = 0; i < 4; ++i) d[tid + i * 256] = s[tid + i * 256];
    }
    if (tid < 64) {
        float su = 0.f, qu = 0.f;
#pragma unroll
        for (int s = 0; s < NSLOT; ++s) {
            su += bnstats[s * 128 + tid];
            qu += bnstats[s * 128 + 64 + tid];
        }
        const float inv = 1.0f / (float)(NB * NN);
        float mu = su * inv;
        float var = qu * inv - mu * mu;
        float sc = gamma[tid] / sqrtf(var + 1e-5f);
        stl[tid] = sc;
        stl[64 + tid] = fmaf(-mu, sc, beta[tid]);
    }
    __syncthreads();

    const float4* __restrict__ in4 = (const float4*)in + (size_t)g * NN * 64;
    int c4 = lane & 15, bi = lane >> 4;
    float4 sv = ((const float4*)stl)[c4];
    float4 tv = ((const float4*)(stl + 64))[c4];
#pragma unroll
    for (int pr = 0; pr < 2; ++pr) {
        int id0 = (pr == 0) ? pid.x : pid.z;
        int id1 = (pr == 0) ? pid.y : pid.w;
        bool vn0 = id0 < NN, vn1 = id1 < NN;
        int rc0 = vn0 ? id0 : 0, rc1 = vn1 ? id1 : 0;
        float dd0 = dinv[rc0]; dd0 *= dd0;
        float dd1 = dinv[rc1]; dd1 *= dd1;
        float4 a0 = {0.f,0.f,0.f,0.f}, a1 = {0.f,0.f,0.f,0.f};
        {
            float4 v0 = actv(in4[(size_t)rc0 * 64 + lane], sv, tv);
            float4 v1 = actv(in4[(size_t)rc1 * 64 + lane], sv, tv);
            if (vn0) { a0.x = dd0 * v0.x; a0.y = dd0 * v0.y; a0.z = dd0 * v0.z; a0.w = dd0 * v0.w; }
            if (vn1) { a1.x = dd1 * v1.x; a1.y = dd1 * v1.y; a1.z = dd1 * v1.z; a1.w = dd1 * v1.w; }
        }
        int p0a = rowptr[rc0], na = vn0 ? (rowptr[rc0 + 1] - p0a) >> 2 : 0;
        int p0b = rowptr[rc1], nbv = vn1 ? (rowptr[rc1 + 1] - p0b) >> 2 : 0;
        int mx = max(na, nbv);
        for (int bb = 0; bb < mx; ++bb) {
            int ea = min(p0a + 4 * bb, NEPAD - 4);
            int eb = min(p0b + 4 * bb, NEPAD - 4);
            bool va = bb < na, vb = bb < nbv;
            int4   ca = *(const int4*)(csr_col + ea);
            float4 wa = *(const float4*)(csr_nv + ea);
            int4   cb = *(const int4*)(csr_col + eb);
            float4 wb = *(const float4*)(csr_nv + eb);
            if (!va) { wa.x = 0.f; wa.y = 0.f; wa.z = 0.f; wa.w = 0.f;
                       ca.x = 0; ca.y = 0; ca.z = 0; ca.w = 0; }   // poisoned tail
            if (!vb) { wb.x = 0.f; wb.y = 0.f; wb.z = 0.f; wb.w = 0.f;
                       cb.x = 0; cb.y = 0; cb.z = 0; cb.w = 0; }
            float4 u0 = in4[(size_t)ca.x * 64 + lane];
            float4 u1 = in4[(size_t)ca.y * 64 + lane];
            float4 u2 = in4[(size_t)ca.z * 64 + lane];
            float4 u3 = in4[(size_t)ca.w * 64 + lane];
            float4 t0 = in4[(size_t)cb.x * 64 + lane];
            float4 t1 = in4[(size_t)cb.y * 64 + lane];
            float4 t2 = in4[(size_t)cb.z * 64 + lane];
            float4 t3 = in4[(size_t)cb.w * 64 + lane];
            fma4(a0, wa.x, actv(u0, sv, tv));
            fma4(a0, wa.y, actv(u1, sv, tv));
            fma4(a0, wa.z, actv(u2, sv, tv));
            fma4(a0, wa.w, actv(u3, sv, tv));
            fma4(a1, wb.x, actv(t0, sv, tv));
            fma4(a1, wb.y, actv(t1, sv, tv));
            fma4(a1, wb.z, actv(t2, sv, tv));
            fma4(a1, wb.w, actv(t3, sv, tv));
        }
        *(float4*)(Aw + ((pr * 2 + 0) * 4 + bi) * ALS + c4 * 4) = a0;
        *(float4*)(Aw + ((pr * 2 + 1) * 4 + bi) * ALS + c4 * 4) = a1;
    }
    // NO __syncthreads here: stage 2 reads only this wave's Aw slice.

    int colq = lane & 15, rowq = lane >> 4;
    int node = (rowq == 0) ? pid.x : (rowq == 1) ? pid.y : (rowq == 2) ? pid.z : pid.w;

    // ---- stage 2: per-wave GEMM from LDS W; thread -> (node rowq, colq) ----
    float4 bb = ((const float4*)bias)[colq];
    float4 o[4];
#pragma unroll
    for (int i = 0; i < 4; ++i) o[i] = bb;
#pragma unroll 8
    for (int k = 0; k < 64; ++k) {
        float4 w4 = ((const float4*)Wl)[k * 16 + colq];
#pragma unroll
        for (int i = 0; i < 4; ++i) {
            float a = Aw[(rowq * 4 + i) * ALS + k];
            fma4(o[i], a, w4);
        }
    }
    if (node < NN) {
        float4* __restrict__ op = (float4*)(out + ((size_t)g * NN + node) * 256);
#pragma unroll
        for (int i = 0; i < 4; ++i) op[i * 16 + colq] = o[i];
    }

    float4 s4 = {0,0,0,0}, q4 = {0,0,0,0};
    if (node < NN) {
#pragma unroll
        for (int i = 0; i < 4; ++i) {
            s4.x += o[i].x; s4.y += o[i].y; s4.z += o[i].z; s4.w += o[i].w;
            q4.x = fmaf(o[i].x, o[i].x, q4.x); q4.y = fmaf(o[i].y, o[i].y, q4.y);
            q4.z = fmaf(o[i].z, o[i].z, q4.z); q4.w = fmaf(o[i].w, o[i].w, q4.w);
        }
    }
    s4.x += __shfl_xor(s4.x, 16); s4.y += __shfl_xor(s4.y, 16);
    s4.z += __shfl_xor(s4.z, 16); s4.w += __shfl_xor(s4.w, 16);
    q4.x += __shfl_xor(q4.x, 16); q4.y += __shfl_xor(q4.y, 16);
    q4.z += __shfl_xor(q4.z, 16); q4.w += __shfl_xor(q4.w, 16);
    s4.x += __shfl_xor(s4.x, 32); s4.y += __shfl_xor(s4.y, 32);
    s4.z += __shfl_xor(s4.z, 32); s4.w += __shfl_xor(s4.w, 32);
    q4.x += __shfl_xor(q4.x, 32); q4.y += __shfl_xor(q4.y, 32);
    q4.z += __shfl_xor(q4.z, 32); q4.w += __shfl_xor(q4.w, 32);
    __syncthreads();   // all waves done with As -> reuse as scratch
    if (lane < 16) {
        float* S = As + wid * 128;
        *(float4*)(S + lane * 8) = s4;
        *(float4*)(S + lane * 8 + 4) = q4;
    }
    __syncthreads();
    if (tid < 64) {
        int cq = tid >> 2, comp = tid & 3;
        float s = 0.f, q = 0.f;
#pragma unroll
        for (int w = 0; w < 4; ++w) {
            s += As[w * 128 + cq * 8 + comp];
            q += As[w * 128 + cq * 8 + 4 + comp];
        }
        float* sl = stats + (blockIdx.x & (NSLOT - 1)) * 128;
        atomicAdd(&sl[tid], s);
        atomicAdd(&sl[64 + tid], q);
    }
}

// ---------------- k_z: z[b,n] = act(h2 row) . W2[:,63] (streaming) ----------
#define ZBLK 2048
__global__ __launch_bounds__(256) void k_z(
        const float* __restrict__ h2, const float* __restrict__ bnstats,
        const float* __restrict__ gamma, const float* __restrict__ beta,
        const float* __restrict__ W2, float* __restrict__ z) {
    __shared__ float stl[128];
    __shared__ float w63[64];
    int tid = threadIdx.x;
    if (tid < 64) {
        float su = 0.f, qu = 0.f;
#pragma unroll
        for (int s = 0; s < NSLOT; ++s) {
            su += bnstats[s * 128 + tid];
            qu += bnstats[s * 128 + 64 + tid];
        }
        const float inv = 1.0f / (float)(NB * NN);
        float mu = su * inv;
        float var = qu * inv - mu * mu;
        float sc = gamma[tid] / sqrtf(var + 1e-5f);
        stl[tid] = sc;
        stl[64 + tid] = fmaf(-mu, sc, beta[tid]);
        w63[tid] = W2[tid * 64 + 63];
    }
    __syncthreads();
    int lane = tid & 63, wid = tid >> 6;
    int c4 = lane & 15;
    float4 sv = ((const float4*)stl)[c4];
    float4 tv = ((const float4*)(stl + 64))[c4];
    float4 w4 = ((const float4*)w63)[c4];
    const int total = NB * NN;   // 256B rows of h2
    for (int base = blockIdx.x * 16; base < total; base += ZBLK * 16) {
        int row = base + wid * 4 + (lane >> 4);
        float s = 0.f;
        if (row < total) {
            float4 v = ((const float4*)h2)[(size_t)row * 16 + c4];
            v.x = fmaxf(fmaf(v.x, sv.x, tv.x), 0.f);
            v.y = fmaxf(fmaf(v.y, sv.y, tv.y), 0.f);
            v.z = fmaxf(fmaf(v.z, sv.z, tv.z), 0.f);
            v.w = fmaxf(fmaf(v.w, sv.w, tv.w), 0.f);
            s = v.x * w4.x + v.y * w4.y + v.z * w4.z + v.w * w4.w;
        }
        s += __shfl_xor(s, 1);
        s += __shfl_xor(s, 2);
        s += __shfl_xor(s, 4);
        s += __shfl_xor(s, 8);
        if ((lane & 15) == 0 && row < total) z[row] = s;
    }
}

// ---------------- k_score: sparse agg of scalar z -> sc (wave per node) -----
__global__ __launch_bounds__(256) void k_score(
        const float* __restrict__ z, const float* __restrict__ b2,
        const int* __restrict__ rowptr, const int* __restrict__ csr_col,
        const float* __restrict__ csr_nv, const float* __restrict__ dinv,
        float* __restrict__ sc) {
    int tid = threadIdx.x;
    int wid = tid >> 6, lane = tid & 63;
    int g = blockIdx.x & 7;
    int nd = (blockIdx.x >> 3) * 4 + wid;   // 1250*4 = 5000 exactly
    if (nd >= NN) return;                   // no barriers below
    const float4* __restrict__ z4 = (const float4*)z + (size_t)g * NN;
    int p0 = rowptr[nd], p1 = rowptr[nd + 1];
    float4 a = {0.f, 0.f, 0.f, 0.f};
    for (int e = p0 + lane; e < p1; e += 64) {
        int col = csr_col[e];
        float nv = csr_nv[e];        // pad entries have nv=0, col=self: safe
        float4 zv = z4[col];
        fma4(a, nv, zv);
    }
#pragma unroll
    for (int off = 1; off < 64; off <<= 1) {
        a.x += __shfl_xor(a.x, off);
        a.y += __shfl_xor(a.y, off);
        a.z += __shfl_xor(a.z, off);
        a.w += __shfl_xor(a.w, off);
    }
    if (lane == 0) {
        float d = dinv[nd]; d *= d;
        float4 zs = z4[nd];
        float bb = b2[63];
        float4 o;
        o.x = fmaxf(fmaf(d, zs.x, a.x) + bb, 0.f);
        o.y = fmaxf(fmaf(d, zs.y, a.y) + bb, 0.f);
        o.z = fmaxf(fmaf(d, zs.z, a.z) + bb, 0.f);
        o.w = fmaxf(fmaf(d, zs.w, a.w) + bb, 0.f);
        ((float4*)sc)[(size_t)g * NN + nd] = o;
    }
}

// ---------------- sort-pool (blocks 0..31, barrier-free) + bnfin (block 32) --
__global__ __launch_bounds__(1024) void k_toppool(const float* __restrict__ sc, int* order,
        const float* __restrict__ stats,
        const float* __restrict__ g0, const float* __restrict__ be0,
        const float* __restrict__ g1, const float* __restrict__ be1,
        float* __restrict__ st) {
    __shared__ unsigned long long cand[16 * KPOOL];
    int tid = threadIdx.x;
    if (blockIdx.x == NB) {
        if (tid < 128) {
            int c = tid & 63, layer = tid >> 6;
            const float* sb = stats + layer * NSLOT * 128;
            float su = 0.f, qu = 0.f;
#pragma unroll
            for (int s = 0; s < NSLOT; ++s) {
                su += sb[s * 128 + c];
                qu += sb[s * 128 + 64 + c];
            }
            const float inv = 1.0f / (float)(NB * NN);
            float mu = su * inv;
            float var = qu * inv - mu * mu;
            float g = layer ? g1[c] : g0[c];
            float be = layer ? be1[c] : be0[c];
            float scv = g / sqrtf(var + 1e-5f);
            st[layer * 128 + c] = scv;
            st[layer * 128 + 64 + c] = fmaf(-mu, scv, be);
        }
        return;
    }
    int b = blockIdx.x;
    int g = b >> 2, bi = b & 3;
    int lane = tid & 63, wid = tid >> 6;
    unsigned long long key[5];
#pragma unroll
    for (int j = 0; j < 5; ++j) {
        int n = tid + j * 1024;
        unsigned long long k = 0;
        if (n < NN) {
            float v = sc[((size_t)g * NN + n) * GB + bi];   // already relu'd
            k = ((unsigned long long)__float_as_uint(v) << 32) | (unsigned int)(NN - n);
        }
        key[j] = k;
    }
    // ---- phase A: per-wave top-30 (no barriers; keys unique -> eq = owner) --
    for (int k = 0; k < KPOOL; ++k) {
        unsigned long long best = key[0];
#pragma unroll
        for (int j = 1; j < 5; ++j) best = (key[j] > best) ? key[j] : best;
#pragma unroll
        for (int off = 1; off < 64; off <<= 1) {
            unsigned long long o = __shfl_xor(best, off);
            best = (o > best) ? o : best;
        }
        if (best) {
#pragma unroll
            for (int j = 0; j < 5; ++j) if (key[j] == best) key[j] = 0;
        }
        if (lane == 0) cand[wid * KPOOL + k] = best;
    }
    __syncthreads();
    // ---- phase B: wave 0 merges 480 candidates -> global top-30 in order ----
    if (wid == 0) {
        unsigned long long r[8];
#pragma unroll
        for (int i = 0; i < 8; ++i) {
            int idx = i * 64 + lane;
            r[i] = (idx < 16 * KPOOL) ? cand[idx] : 0;
        }
        for (int k = 0; k < KPOOL; ++k) {
            unsigned long long best = r[0];
#pragma unroll
            for (int i = 1; i < 8; ++i) best = (r[i] > best) ? r[i] : best;
#pragma unroll
            for (int off = 1; off < 64; off <<= 1) {
                unsigned long long o = __shfl_xor(best, off);
                best = (o > best) ? o : best;
            }
            if (best) {
#pragma unroll
                for (int i = 0; i < 8; ++i) if (r[i] == best) r[i] = 0;
            }
            if (lane == 0) order[b * KPOOL + k] = NN - (int)(best & 0xFFFFFFFFu);
        }
    }
}

// ---------------- gather selected nodes into flat (B, 6241) ----------------
// Aggregates the h3 row for this (b,node) from act(h2) (only 960 pairs — R30),
// then the 64x64 GEMM from LDS (W2 cached in LDS — R33).
__global__ void k_gather(const float* __restrict__ xt, const float* __restrict__ h1,
                         const float* __restrict__ h2,
                         const float* __restrict__ W2, const float* __restrict__ b2,
                         const float* __restrict__ st, const float* __restrict__ age,
                         const int* __restrict__ rowptr, const int* __restrict__ csr_col,
                         const float* __restrict__ csr_nv, const float* __restrict__ dinv,
                         const int* __restrict__ order, float* __restrict__ flat) {
    __shared__ float aggP[4][64];
    __shared__ float aggRow[64];
    __shared__ float W2l[64 * 64];
    int bk = blockIdx.x;
    int b = bk / KPOOL, k = bk % KPOOL;
    int n = order[bk];
    int g = b >> 2, bi = b & 3;
    size_t node = (size_t)g * NN + n;
    int tid = threadIdx.x;
    {   // W2 -> LDS (coalesced, 4 float4 per thread)
        float4* d = (float4*)W2l;
        const float4* s = (const float4*)W2;
#pragma unroll
        for (int i = 0; i < 4; ++i) d[tid + i * 256] = s[tid + i * 256];
    }
    // ---- phase 1: 4-way edge-split aggregation of act(h2) row ----
    {
        int ep = tid >> 6, c = tid & 63;
        float sc1 = st[128 + c], sh1 = st[192 + c];
        float a = 0.f;
        if (ep == 0) {
            float d = dinv[n];
            float v = h2[(node * GB + bi) * CH + c];
            a = d * d * fmaxf(fmaf(v, sc1, sh1), 0.f);
        }
        int p0 = rowptr[n], p1 = rowptr[n + 1];
        for (int e = p0 + ep; e < p1; e += 4) {
            int col = csr_col[e];
            float nv = csr_nv[e];    // pad entries nv=0: safe
            float v = h2[(((size_t)g * NN + col) * GB + bi) * CH + c];
            a += nv * fmaxf(fmaf(v, sc1, sh1), 0.f);
        }
        aggP[ep][c] = a;
    }
    __syncthreads();
    if (tid < 64) aggRow[tid] = aggP[0][tid] + aggP[1][tid] + aggP[2][tid] + aggP[3][tid];
    __syncthreads();
    // ---- phase 2: feature assembly ----
    int f = tid;
    float val = 0.f;
    if (f < DIN) {
        val = xt[(((size_t)(b >> 3) * NN + n) * 8 + (b & 7)) * DIN + f];   // G4 layout
    } else if (f < DIN + CH) {
        int c = f - DIN;
        val = fmaxf(fmaf(h1[(node * GB + bi) * CH + c], st[c], st[64 + c]), 0.f);
    } else if (f < DIN + 2 * CH) {
        int c = f - DIN - CH;
        val = fmaxf(fmaf(h2[(node * GB + bi) * CH + c], st[128 + c], st[192 + c]), 0.f);
    } else if (f < FTOT) {
        int c = f - DIN - 2 * CH;
        float s = b2[c];
#pragma unroll 8
        for (int kk = 0; kk < 64; ++kk)
            s = fmaf(aggRow[kk], W2l[kk * 64 + c], s);
        val = fmaxf(s, 0.f);
    }
    if (f < FTOT) flat[(size_t)b * FLATW + k * FTOT + f] = val;
    if (bk == 0 && f >= FTOT && f < FTOT + NB)
        flat[(size_t)(f - FTOT) * FLATW + (FLATW - 1)] = age[f - FTOT];
}

// ---------------- MLP head layer 1: hm += flat @ mW0 (k-split, atomics) ----------------
__global__ void k_head1(const float* __restrict__ flat, const float* __restrict__ mW0,
                        float* hm) {
    int tid = threadIdx.x;
    int j4 = (tid & 31) * 4;       // 32 groups * 4 = 128 cols
    int b0 = (tid >> 5) * 4;       // 8 groups * 4 = 32 rows
    int kbase = blockIdx.x * 64;
    float acc[4][4];
#pragma unroll
    for (int i = 0; i < 4; i++)
#pragma unroll
        for (int jj = 0; jj < 4; jj++) acc[i][jj] = 0.f;
    int kend = FLATW - kbase; if (kend > 64) kend = 64;
    for (int kk = 0; kk < kend; ++kk) {
        int k = kbase + kk;
        float4 w = *(const float4*)(mW0 + (size_t)k * NH + j4);
#pragma unroll
        for (int i = 0; i < 4; i++) {
            float fv = flat[(size_t)(b0 + i) * FLATW + k];
            acc[i][0] = fmaf(fv, w.x, acc[i][0]);
            acc[i][1] = fmaf(fv, w.y, acc[i][1]);
            acc[i][2] = fmaf(fv, w.z, acc[i][2]);
            acc[i][3] = fmaf(fv, w.w, acc[i][3]);
        }
    }
#pragma unroll
    for (int i = 0; i < 4; i++)
#pragma unroll
        for (int jj = 0; jj < 4; jj++)
            atomicAdd(&hm[(size_t)(b0 + i) * NH + j4 + jj], acc[i][jj]);
}

// ---------------- head layer 2 + log_softmax (4-way j-split) ----------------
__global__ void k_head2(const float* __restrict__ hm, const float* __restrict__ mb0,
                        const float* __restrict__ mW1, const float* __restrict__ mb1,
                        float* __restrict__ out) {
    __shared__ float part[256];
    __shared__ float vals[64];
    int tid = threadIdx.x;  // 256 = 32b * 2o * 4q
    int q = tid & 3, o = (tid >> 2) & 1, b = tid >> 3;
    float acc = 0.f;
    for (int j = q * 32; j < q * 32 + 32; ++j) {
        float hv = fmaxf(hm[b * NH + j] + mb0[j], 0.f);
        acc = fmaf(hv, mW1[j * 2 + o], acc);
    }
    part[tid] = acc;
    __syncthreads();
    if (tid < 64) {
        int b2 = tid >> 1, o2 = tid & 1;
        int base = (b2 << 3) + (o2 << 2);
        vals[tid] = part[base] + part[base + 1] + part[base + 2] + part[base + 3] + mb1[o2];
    }
    __syncthreads();
    if (tid < 64) {
        int b2 = tid >> 1;
        float v0 = vals[b2 * 2], v1 = vals[b2 * 2 + 1];
        float m = fmaxf(v0, v1);
        float lse = m + logf(expf(v0 - m) + expf(v1 - m));
        out[tid] = vals[tid] - lse;
    }
}

extern "C" void kernel_launch(void* const* d_in, const int* in_sizes, int n_in,
                              void* d_out, int out_size, void* d_ws, size_t ws_size,
                              hipStream_t stream) {
    const float* x    = (const float*)d_in[0];
    const float* age  = (const float*)d_in[1];
    const float* attr = (const float*)d_in[2];
    const float* W0   = (const float*)d_in[3];
    const float* b0   = (const float*)d_in[4];
    const float* W1   = (const float*)d_in[5];
    const float* b1   = (const float*)d_in[6];
    const float* W2   = (const float*)d_in[7];
    const float* b2   = (const float*)d_in[8];
    const float* g0   = (const float*)d_in[9];
    const float* be0  = (const float*)d_in[10];
    const float* g1   = (const float*)d_in[11];
    const float* be1  = (const float*)d_in[12];
    const float* mW0  = (const float*)d_in[13];
    const float* mb0  = (const float*)d_in[14];
    const float* mW1  = (const float*)d_in[15];
    const float* mb1  = (const float*)d_in[16];
    const int* erow   = (const int*)d_in[17];
    const int* ecol   = (const int*)d_in[18];
    float* out = (float*)d_out;

    // workspace layout (floats); all float4-aligned
    float* ws     = (float*)d_ws;
    float* deg    = ws;                                  // 5008
    float* dinv   = deg + 5008;                          // 5008
    int*   counts = (int*)(dinv + 5008);                 // 5008
    int*   rowptr = counts + 5008;                       // 5008
    int*   cursor = rowptr + 5008;                       // 5008
    int*   perm   = cursor + 5008;                       // 5008
    int*   csr_col= perm + 5008;                         // NEPAD
    float* csr_nv = (float*)(csr_col + NEPAD);           // NEPAD
    float* stats  = csr_nv + NEPAD;                      // 2*32*128 = 8192
    float* st     = stats + 2 * NSLOT * 128;             // 256 (s0,t0,s1,t1)
    float* sc     = st + 256;                            // NG*NN*4 = 160000 (scores)
    int*   order  = (int*)(sc + NB * NN);                // 960
    float* flat   = (float*)(order + 960);               // 32*6241
    float* hm     = flat + (size_t)NB * FLATW;           // 4096
    float* xt     = hm + 4096;                           // (G4,N,8,16)
    float* h1     = xt + (size_t)NB * NN * DIN;          // (G8,N,4,64) each
    float* h2     = h1 + (size_t)NB * NN * CH;
    float* z      = h2 + (size_t)NB * NN * CH;           // NG*NN*4 = 160000

    // graph build: scan+sort+transpose share one dispatch (concurrent roles)
    k_init<<<32, 256, 0, stream>>>(deg, counts, stats, hm, perm);
    k_edges<<<NEB, 256, 0, stream>>>(attr, erow, deg, counts);
    k_phase1<<<2 + (NB * NN + 1023) / 1024, 1024, 0, stream>>>(counts, deg, rowptr, cursor, dinv, perm, x, xt);
    k_build<<<(NE + NN + 1023) / 1024, 1024, 0, stream>>>(erow, ecol, attr, dinv, counts, rowptr, cursor, csr_col, csr_nv);

    // conv0 (G4) + conv1 (G8, LDS-cached W); conv2 = z/score/gather-agg (R30)
    k_l16<<<NCHUNK * 4, 256, 0, stream>>>(xt, W0, b0, rowptr, csr_col, csr_nv, dinv, perm, h1, stats);
    k_l64<<<NCHUNK * NG, 256, 0, stream>>>(h1, stats, g0, be0, W1, b1, rowptr, csr_col, csr_nv, dinv, perm, h2, stats + NSLOT * 128);
    k_z<<<ZBLK, 256, 0, stream>>>(h2, stats + NSLOT * 128, g1, be1, W2, z);
    k_score<<<(NN / 4) * NG, 256, 0, stream>>>(z, b2, rowptr, csr_col, csr_nv, dinv, sc);

    // sort-pool (barrier-free, +fused bnfin) + gather (inline agg) + head
    k_toppool<<<NB + 1, 1024, 0, stream>>>(sc, order, stats, g0, be0, g1, be1, st);
    k_gather<<<NB * KPOOL, 256, 0, stream>>>(xt, h1, h2, W2, b2, st, age, rowptr, csr_col, csr_nv, dinv, order, flat);
    k_head1<<<(FLATW + 63) / 64, 256, 0, stream>>>(flat, mW0, hm);
    k_head2<<<1, 256, 0, stream>>>(hm, mb0, mW1, mb1, out);
}

// Round 14
// 299.751 us; speedup vs baseline: 1.0624x; 1.0200x over previous
//
#include <hip/hip_runtime.h>
#include <math.h>

// Problem constants (from reference setup_inputs)
#define NN    5000      // nodes
#define NE    80000     // edges
#define NB    32        // batch
#define DIN   16        // input feat
#define CH    64        // conv channels
#define KPOOL 30
#define FTOT  208      // 16 + 3*64
#define FLATW 6241     // KPOOL*FTOT + 1
#define NH    128      // MLP hidden
#define NG    8        // batch groups for CIN64 layer (one per XCD)
#define GB    4        // batches per group (h1/h2 layout)
#define NPB   16       // nodes per block (4 per wave)
#define NCHUNK 313     // node chunks (blocks per group)
#define NPAD  5008     // perm array size
#define NEPAD (NE + 4 * NN)   // CSR rows padded to multiple of 4
#define NSLOT 32       // stats atomic-spread slots

// Journal: R19 ordering / R20+R24 occupancy: dead. R21 CSR rotate: neutral.
// R22 act-hoist: -43% VALU -> -5% dur. R26 serial-merge: 354 -> 348.6.
// R27/28 batch-half: pass-doubling loses. R29 wide rows: VGPR cliff.
// R30 conv2 killed algebraically: 348.6 -> 316.5. R31/R32: neutral.
// R33 LDS-cached W: k_l64 71.4 -> 64.6, total 305.8 — VMEM-INSTRUCTION-RATE
// MODEL CONFIRMED (time ~ # vector-memory instructions; width/hit/VALU nearly
// free; occupancy 36% and still faster). R34 (this): the 4 CSR loads per
// loop iteration (of 12 VMEM) have WAVE-UNIFORM addresses (derived from pid).
// Route pid through readfirstlane -> SGPRs -> compiler emits s_load on the
// SCALAR pipe (lgkmcnt, no vector-port cost). Loop VMEM 12 -> 8 per iter.
// Applied to k_l64 + k_l16.

// ---------------- setup kernels ----------------

__global__ void k_init(float* deg, int* counts, float* stats, float* hm, int* perm) {
    int i = blockIdx.x * 256 + threadIdx.x;
    if (i < NN) { deg[i] = 1.0f; counts[i] = 0; }   // deg starts at self-loop value 1
    if (i < 2 * NSLOT * 128) stats[i] = 0.0f;       // [2 layers][32 slots][128]
    if (i < 4096) hm[i] = 0.0f;
    if (i >= NN && i < NPAD) perm[i] = NN;          // tail -> invalid marker
}

#define NEB 313
__global__ void k_edges(const float* __restrict__ attr, const int* __restrict__ erow,
                        float* deg, int* counts) {
    int e = blockIdx.x * 256 + threadIdx.x;
    if (e < NE) {
        int r = erow[e];
        atomicAdd(&deg[r], attr[e]);
        atomicAdd(&counts[r], 1);
    }
}

// merged concurrent phase: block 0 = prefix scan, block 1 = counting sort,
// blocks 2.. = x transpose to (G4,N,8,16) (serial roles hide under transpose).
__global__ __launch_bounds__(1024) void k_phase1(
        const int* __restrict__ counts, const float* __restrict__ deg,
        int* rowptr, int* cursor, float* dinv, int* perm,
        const float* __restrict__ x, float* __restrict__ xt) {
    __shared__ int wsum[16], woff[16];
    __shared__ int carry_sh;
    __shared__ int hist[256];
    int t = threadIdx.x;
    if (blockIdx.x >= 2) {
        int idx = (blockIdx.x - 2) * 1024 + t;
        if (idx >= NB * NN) return;
        int b = idx / NN, n = idx % NN;
        int g4 = b >> 3, bi8 = b & 7;
        const float4* src = (const float4*)(x + (size_t)idx * DIN);
        float4* dst = (float4*)(xt + (((size_t)g4 * NN + n) * 8 + bi8) * DIN);
        dst[0] = src[0]; dst[1] = src[1]; dst[2] = src[2]; dst[3] = src[3];
        return;
    }
    if (blockIdx.x == 0) {
        int lane = t & 63, wid = t >> 6;
        if (t == 0) carry_sh = 0;
        __syncthreads();
        for (int base = 0; base < NN; base += 1024) {
            int carry = carry_sh;
            int i = base + t;
            int v = 0;
            if (i < NN) {
                v = (counts[i] + 3) & ~3;
                dinv[i] = 1.0f / sqrtf(deg[i]);   // deg >= 1 always
            }
            int s = v;
#pragma unroll
            for (int off = 1; off < 64; off <<= 1) {
                int o = __shfl_up(s, off);
                if (lane >= off) s += o;
            }
            if (lane == 63) wsum[wid] = s;
            __syncthreads();
            if (t < 16) {
                int w = wsum[t];
#pragma unroll
                for (int off = 1; off < 16; off <<= 1) {
                    int o = __shfl_up(w, off);
                    if (t >= off) w += o;
                }
                woff[t] = w;
            }
            __syncthreads();
            int inc = s + (wid > 0 ? woff[wid - 1] : 0) + carry;
            if (i < NN) {
                rowptr[i + 1] = inc;
                cursor[i] = inc - v;
            }
            if (t == 1023) carry_sh = carry + woff[15];
            __syncthreads();
        }
        if (t == 0) rowptr[0] = 0;
    } else {
        if (t < 256) hist[t] = 0;
        __syncthreads();
        for (int i = t; i < NN; i += 1024) {
            int b = 255 - min(((counts[i] + 3) & ~3) >> 2, 255);
            atomicAdd(&hist[b], 1);
        }
        __syncthreads();
        int mycnt = (t < 256) ? hist[t] : 0;
        for (int off = 1; off < 256; off <<= 1) {
            int v = (t < 256 && t >= off) ? hist[t - off] : 0;
            __syncthreads();
            if (t < 256) hist[t] += v;
            __syncthreads();
        }
        if (t < 256) hist[t] -= mycnt;
        __syncthreads();
        for (int i = t; i < NN; i += 1024) {
            int b = 255 - min(((counts[i] + 3) & ~3) >> 2, 255);
            int pos = atomicAdd(&hist[b], 1);
            perm[pos] = i;
        }
    }
}

__global__ __launch_bounds__(1024) void k_build(
        const int* __restrict__ erow, const int* __restrict__ ecol,
        const float* __restrict__ attr, const float* __restrict__ dinv,
        const int* __restrict__ counts, const int* __restrict__ rowptr,
        int* cursor, int* csr_col, float* csr_nv) {
    int t = blockIdx.x * 1024 + threadIdx.x;
    if (t < NE) {
        int r = erow[t], c = ecol[t];
        int pos = atomicAdd(&cursor[r], 1);
        csr_col[pos] = c;
        csr_nv[pos] = dinv[r] * attr[t] * dinv[c];
    } else if (t - NE < NN) {
        int i = t - NE;
        int cnt = counts[i];
        int pcnt = (cnt + 3) & ~3;
        int base = rowptr[i + 1] - pcnt;
        for (int p = base + cnt; p < base + pcnt; ++p) { csr_col[p] = i; csr_nv[p] = 0.0f; }
    }
}

// ---------------- helpers ----------------
__device__ __forceinline__ float4 actv(float4 v, float4 s, float4 t) {
    v.x = fmaxf(fmaf(v.x, s.x, t.x), 0.f);
    v.y = fmaxf(fmaf(v.y, s.y, t.y), 0.f);
    v.z = fmaxf(fmaf(v.z, s.z, t.z), 0.f);
    v.w = fmaxf(fmaf(v.w, s.w, t.w), 0.f);
    return v;
}
__device__ __forceinline__ void fma4(float4& a, float w, float4 v) {
    a.x = fmaf(w, v.x, a.x); a.y = fmaf(w, v.y, a.y);
    a.z = fmaf(w, v.z, a.z); a.w = fmaf(w, v.w, a.w);
}
__device__ __forceinline__ void fma2(float2& a, float w, float2 v) {
    a.x = fmaf(w, v.x, a.x); a.y = fmaf(w, v.y, a.y);
}

// ---------------- layer 0 (CIN=16, G4): xt (G4,N,8,16) -> h1 (G8,N,4,64) ----
__global__ __launch_bounds__(256) void k_l16(
        const float* __restrict__ in,
        const float* __restrict__ W, const float* __restrict__ bias,
        const int* __restrict__ rowptr, const int* __restrict__ csr_col,
        const float* __restrict__ csr_nv, const float* __restrict__ dinv,
        const int* __restrict__ perm,
        float* __restrict__ out, float* __restrict__ stats) {
    const int ALS = 18;
    __shared__ float As[4 * 32 * ALS];   // 9216 B
    __shared__ float Wl[16 * 64];        // R33: W cached in LDS (4 KB)
    int tid = threadIdx.x;
    int wid = tid >> 6, lane = tid & 63;
    int g4 = blockIdx.x & 3;
    int base = (blockIdx.x >> 2) * NPB + wid * 4;
    float* Aw = As + wid * 32 * ALS;
    const int4 pidv = *(const int4*)(perm + base);
    int4 pid;   // R34: scalarize -> downstream CSR/rowptr loads use s_load pipe
    pid.x = __builtin_amdgcn_readfirstlane(pidv.x);
    pid.y = __builtin_amdgcn_readfirstlane(pidv.y);
    pid.z = __builtin_amdgcn_readfirstlane(pidv.z);
    pid.w = __builtin_amdgcn_readfirstlane(pidv.w);

    ((float4*)Wl)[tid] = ((const float4*)W)[tid];   // 256 float4 = whole W
    __syncthreads();

    const float2* __restrict__ in2 = (const float2*)in + (size_t)g4 * NN * 64; // row = 64 f2
    int bi8 = lane >> 3, chp = lane & 7;   // (batch-of-8, ch-pair)

#pragma unroll
    for (int pr = 0; pr < 2; ++pr) {
        int id0 = (pr == 0) ? pid.x : pid.z;
        int id1 = (pr == 0) ? pid.y : pid.w;
        bool vn0 = id0 < NN, vn1 = id1 < NN;
        int rc0 = vn0 ? id0 : 0, rc1 = vn1 ? id1 : 0;
        float dd0 = dinv[rc0]; dd0 *= dd0;
        float dd1 = dinv[rc1]; dd1 *= dd1;
        float2 a0 = {0.f, 0.f}, a1 = {0.f, 0.f};
        {
            float2 v0 = in2[(size_t)rc0 * 64 + lane];
            float2 v1 = in2[(size_t)rc1 * 64 + lane];
            if (vn0) { a0.x = dd0 * v0.x; a0.y = dd0 * v0.y; }
            if (vn1) { a1.x = dd1 * v1.x; a1.y = dd1 * v1.y; }
        }
        int p0a = rowptr[rc0], na = vn0 ? (rowptr[rc0 + 1] - p0a) >> 2 : 0;
        int p0b = rowptr[rc1], nbv = vn1 ? (rowptr[rc1 + 1] - p0b) >> 2 : 0;
        int mx = max(na, nbv);
        for (int bb = 0; bb < mx; ++bb) {
            int ea = min(p0a + 4 * bb, NEPAD - 4);
            int eb = min(p0b + 4 * bb, NEPAD - 4);
            bool va = bb < na, vb = bb < nbv;
            int4   ca = *(const int4*)(csr_col + ea);
            float4 wa = *(const float4*)(csr_nv + ea);
            int4   cb = *(const int4*)(csr_col + eb);
            float4 wb = *(const float4*)(csr_nv + eb);
            if (!va) { wa.x = 0.f; wa.y = 0.f; wa.z = 0.f; wa.w = 0.f;
                       ca.x = 0; ca.y = 0; ca.z = 0; ca.w = 0; }   // poisoned tail
            if (!vb) { wb.x = 0.f; wb.y = 0.f; wb.z = 0.f; wb.w = 0.f;
                       cb.x = 0; cb.y = 0; cb.z = 0; cb.w = 0; }
            float2 u0 = in2[(size_t)ca.x * 64 + lane];
            float2 u1 = in2[(size_t)ca.y * 64 + lane];
            float2 u2 = in2[(size_t)ca.z * 64 + lane];
            float2 u3 = in2[(size_t)ca.w * 64 + lane];
            float2 t0 = in2[(size_t)cb.x * 64 + lane];
            float2 t1 = in2[(size_t)cb.y * 64 + lane];
            float2 t2 = in2[(size_t)cb.z * 64 + lane];
            float2 t3 = in2[(size_t)cb.w * 64 + lane];
            fma2(a0, wa.x, u0);
            fma2(a0, wa.y, u1);
            fma2(a0, wa.z, u2);
            fma2(a0, wa.w, u3);
            fma2(a1, wb.x, t0);
            fma2(a1, wb.y, t1);
            fma2(a1, wb.z, t2);
            fma2(a1, wb.w, t3);
        }
        *(float2*)(Aw + ((2 * pr + 0) * 8 + bi8) * ALS + chp * 2) = a0;
        *(float2*)(Aw + ((2 * pr + 1) * 8 + bi8) * ALS + chp * 2) = a1;
    }
    // NO barrier: stage 2 reads only this wave's Aw slice.

    int colq = lane & 15, rowq = lane >> 4;
    int node = (rowq == 0) ? pid.x : (rowq == 1) ? pid.y : (rowq == 2) ? pid.z : pid.w;

    float4 bb4 = ((const float4*)bias)[colq];
    float4 o[8];
#pragma unroll
    for (int i = 0; i < 8; ++i) o[i] = bb4;
#pragma unroll
    for (int k = 0; k < 16; ++k) {
        float4 w4 = ((const float4*)Wl)[k * 16 + colq];
#pragma unroll
        for (int i = 0; i < 8; ++i)
            fma4(o[i], Aw[(rowq * 8 + i) * ALS + k], w4);
    }
    if (node < NN) {
#pragma unroll
        for (int i = 0; i < 8; ++i) {
            int g8 = g4 * 2 + (i >> 2);
            float4* op = (float4*)(out + (((size_t)g8 * NN + node) * 4 + (i & 3)) * 64);
            op[colq] = o[i];
        }
    }

    // stats (layer 0): lane sums its 8 batches; shfl sums over nodes
    float4 s4 = {0,0,0,0}, q4 = {0,0,0,0};
    if (node < NN) {
#pragma unroll
        for (int i = 0; i < 8; ++i) {
            s4.x += o[i].x; s4.y += o[i].y; s4.z += o[i].z; s4.w += o[i].w;
            q4.x = fmaf(o[i].x, o[i].x, q4.x); q4.y = fmaf(o[i].y, o[i].y, q4.y);
            q4.z = fmaf(o[i].z, o[i].z, q4.z); q4.w = fmaf(o[i].w, o[i].w, q4.w);
        }
    }
    s4.x += __shfl_xor(s4.x, 16); s4.y += __shfl_xor(s4.y, 16);
    s4.z += __shfl_xor(s4.z, 16); s4.w += __shfl_xor(s4.w, 16);
    q4.x += __shfl_xor(q4.x, 16); q4.y += __shfl_xor(q4.y, 16);
    q4.z += __shfl_xor(q4.z, 16); q4.w += __shfl_xor(q4.w, 16);
    s4.x += __shfl_xor(s4.x, 32); s4.y += __shfl_xor(s4.y, 32);
    s4.z += __shfl_xor(s4.z, 32); s4.w += __shfl_xor(s4.w, 32);
    q4.x += __shfl_xor(q4.x, 32); q4.y += __shfl_xor(q4.y, 32);
    q4.z += __shfl_xor(q4.z, 32); q4.w += __shfl_xor(q4.w, 32);
    __syncthreads();   // all waves done with As -> reuse as scratch
    if (lane < 16) {
        float* S = As + wid * 128;
        *(float4*)(S + lane * 8) = s4;
        *(float4*)(S + lane * 8 + 4) = q4;
    }
    __syncthreads();
    if (tid < 64) {
        int cq = tid >> 2, comp = tid & 3;
        float s = 0.f, q = 0.f;
#pragma unroll
        for (int w = 0; w < 4; ++w) {
            s += As[w * 128 + cq * 8 + comp];
            q += As[w * 128 + cq * 8 + 4 + comp];
        }
        float* sl = stats + (blockIdx.x & (NSLOT - 1)) * 128;
        atomicAdd(&sl[tid], s);
        atomicAdd(&sl[64 + tid], q);
    }
}

// ---------------- fused CIN64 GCN layer (LDS W + scalar CSR pipe) -----------
__global__ __launch_bounds__(256) void k_l64(
        const float* __restrict__ in, const float* __restrict__ bnstats,
        const float* __restrict__ gamma, const float* __restrict__ beta,
        const float* __restrict__ W, const float* __restrict__ bias,
        const int* __restrict__ rowptr, const int* __restrict__ csr_col,
        const float* __restrict__ csr_nv, const float* __restrict__ dinv,
        const int* __restrict__ perm,
        float* __restrict__ out, float* __restrict__ stats) {
    const int ALS = 68;
    __shared__ float As[4 * 16 * ALS];
    __shared__ float stl[128];
    __shared__ float Wl[64 * 64];        // R33: W cached in LDS (16 KB)
    int tid = threadIdx.x;
    int wid = tid >> 6, lane = tid & 63;
    int g = blockIdx.x & 7;                      // XCD round-robin
    int base = (blockIdx.x >> 3) * NPB + wid * 4;
    float* Aw = As + wid * 16 * ALS;
    const int4 pidv = *(const int4*)(perm + base);
    int4 pid;   // R34: scalarize -> CSR/rowptr/dinv loads go to the s_load pipe
    pid.x = __builtin_amdgcn_readfirstlane(pidv.x);
    pid.y = __builtin_amdgcn_readfirstlane(pidv.y);
    pid.z = __builtin_amdgcn_readfirstlane(pidv.z);
    pid.w = __builtin_amdgcn_readfirstlane(pidv.w);

    {   // W -> LDS: 1024 float4, coalesced, 4 per thread
        float4* d = (float4*)Wl;
        const float4* s = (const float4*)W;
#pragma unroll
        for (int i = 0; i < 4; ++i) d[tid + i * 256] = s[tid + i * 256];
    }
    if (tid < 64) {
        float su = 0.f, qu = 0.f;
#pragma unroll
        for (int s = 0; s < NSLOT; ++s) {
            su += bnstats[s * 128 + tid];
            qu += bnstats[s * 128 + 64 + tid];
        }
        const float inv = 1.0f / (float)(NB * NN);
        float mu = su * inv;
        float var = qu * inv - mu * mu;
        float sc = gamma[tid] / sqrtf(var + 1e-5f);
        stl[tid] = sc;
        stl[64 + tid] = fmaf(-mu, sc, beta[tid]);
    }
    __syncthreads();

    const float4* __restrict__ in4 = (const float4*)in + (size_t)g * NN * 64;
    int c4 = lane & 15, bi = lane >> 4;
    float4 sv = ((const float4*)stl)[c4];
    float4 tv = ((const float4*)(stl + 64))[c4];
#pragma unroll
    for (int pr = 0; pr < 2; ++pr) {
        int id0 = (pr == 0) ? pid.x : pid.z;
        int id1 = (pr == 0) ? pid.y : pid.w;
        bool vn0 = id0 < NN, vn1 = id1 < NN;
        int rc0 = vn0 ? id0 : 0, rc1 = vn1 ? id1 : 0;
        float dd0 = dinv[rc0]; dd0 *= dd0;
        float dd1 = dinv[rc1]; dd1 *= dd1;
        float4 a0 = {0.f,0.f,0.f,0.f}, a1 = {0.f,0.f,0.f,0.f};
        {
            float4 v0 = actv(in4[(size_t)rc0 * 64 + lane], sv, tv);
            float4 v1 = actv(in4[(size_t)rc1 * 64 + lane], sv, tv);
            if (vn0) { a0.x = dd0 * v0.x; a0.y = dd0 * v0.y; a0.z = dd0 * v0.z; a0.w = dd0 * v0.w; }
            if (vn1) { a1.x = dd1 * v1.x; a1.y = dd1 * v1.y; a1.z = dd1 * v1.z; a1.w = dd1 * v1.w; }
        }
        int p0a = rowptr[rc0], na = vn0 ? (rowptr[rc0 + 1] - p0a) >> 2 : 0;
        int p0b = rowptr[rc1], nbv = vn1 ? (rowptr[rc1 + 1] - p0b) >> 2 : 0;
        int mx = max(na, nbv);
        for (int bb = 0; bb < mx; ++bb) {
            int ea = min(p0a + 4 * bb, NEPAD - 4);
            int eb = min(p0b + 4 * bb, NEPAD - 4);
            bool va = bb < na, vb = bb < nbv;
            int4   ca = *(const int4*)(csr_col + ea);
            float4 wa = *(const float4*)(csr_nv + ea);
            int4   cb = *(const int4*)(csr_col + eb);
            float4 wb = *(const float4*)(csr_nv + eb);
            if (!va) { wa.x = 0.f; wa.y = 0.f; wa.z = 0.f; wa.w = 0.f;
                       ca.x = 0; ca.y = 0; ca.z = 0; ca.w = 0; }   // poisoned tail
            if (!vb) { wb.x = 0.f; wb.y = 0.f; wb.z = 0.f; wb.w = 0.f;
                       cb.x = 0; cb.y = 0; cb.z = 0; cb.w = 0; }
            float4 u0 = in4[(size_t)ca.x * 64 + lane];
            float4 u1 = in4[(size_t)ca.y * 64 + lane];
            float4 u2 = in4[(size_t)ca.z * 64 + lane];
            float4 u3 = in4[(size_t)ca.w * 64 + lane];
            float4 t0 = in4[(size_t)cb.x * 64 + lane];
            float4 t1 = in4[(size_t)cb.y * 64 + lane];
            float4 t2 = in4[(size_t)cb.z * 64 + lane];
            float4 t3 = in4[(size_t)cb.w * 64 + lane];
            fma4(a0, wa.x, actv(u0, sv, tv));
            fma4(a0, wa.y, actv(u1, sv, tv));
            fma4(a0, wa.z, actv(u2, sv, tv));
            fma4(a0, wa.w, actv(u3, sv, tv));
            fma4(a1, wb.x, actv(t0, sv, tv));
            fma4(a1, wb.y, actv(t1, sv, tv));
            fma4(a1, wb.z, actv(t2, sv, tv));
            fma4(a1, wb.w, actv(t3, sv, tv));
        }
        *(float4*)(Aw + ((pr * 2 + 0) * 4 + bi) * ALS + c4 * 4) = a0;
        *(float4*)(Aw + ((pr * 2 + 1) * 4 + bi) * ALS + c4 * 4) = a1;
    }
    // NO __syncthreads here: stage 2 reads only this wave's Aw slice.

    int colq = lane & 15, rowq = lane >> 4;
    int node = (rowq == 0) ? pid.x : (rowq == 1) ? pid.y : (rowq == 2) ? pid.z : pid.w;

    // ---- stage 2: per-wave GEMM from LDS W; thread -> (node rowq, colq) ----
    float4 bb = ((const float4*)bias)[colq];
    float4 o[4];
#pragma unroll
    for (int i = 0; i < 4; ++i) o[i] = bb;
#pragma unroll 8
    for (int k = 0; k < 64; ++k) {
        float4 w4 = ((const float4*)Wl)[k * 16 + colq];
#pragma unroll
        for (int i = 0; i < 4; ++i) {
            float a = Aw[(rowq * 4 + i) * ALS + k];
            fma4(o[i], a, w4);
        }
    }
    if (node < NN) {
        float4* __restrict__ op = (float4*)(out + ((size_t)g * NN + node) * 256);
#pragma unroll
        for (int i = 0; i < 4; ++i) op[i * 16 + colq] = o[i];
    }

    float4 s4 = {0,0,0,0}, q4 = {0,0,0,0};
    if (node < NN) {
#pragma unroll
        for (int i = 0; i < 4; ++i) {
            s4.x += o[i].x; s4.y += o[i].y; s4.z += o[i].z; s4.w += o[i].w;
            q4.x = fmaf(o[i].x, o[i].x, q4.x); q4.y = fmaf(o[i].y, o[i].y, q4.y);
            q4.z = fmaf(o[i].z, o[i].z, q4.z); q4.w = fmaf(o[i].w, o[i].w, q4.w);
        }
    }
    s4.x += __shfl_xor(s4.x, 16); s4.y += __shfl_xor(s4.y, 16);
    s4.z += __shfl_xor(s4.z, 16); s4.w += __shfl_xor(s4.w, 16);
    q4.x += __shfl_xor(q4.x, 16); q4.y += __shfl_xor(q4.y, 16);
    q4.z += __shfl_xor(q4.z, 16); q4.w += __shfl_xor(q4.w, 16);
    s4.x += __shfl_xor(s4.x, 32); s4.y += __shfl_xor(s4.y, 32);
    s4.z += __shfl_xor(s4.z, 32); s4.w += __shfl_xor(s4.w, 32);
    q4.x += __shfl_xor(q4.x, 32); q4.y += __shfl_xor(q4.y, 32);
    q4.z += __shfl_xor(q4.z, 32); q4.w += __shfl_xor(q4.w, 32);
    __syncthreads();   // all waves done with As -> reuse as scratch
    if (lane < 16) {
        float* S = As + wid * 128;
        *(float4*)(S + lane * 8) = s4;
        *(float4*)(S + lane * 8 + 4) = q4;
    }
    __syncthreads();
    if (tid < 64) {
        int cq = tid >> 2, comp = tid & 3;
        float s = 0.f, q = 0.f;
#pragma unroll
        for (int w = 0; w < 4; ++w) {
            s += As[w * 128 + cq * 8 + comp];
            q += As[w * 128 + cq * 8 + 4 + comp];
        }
        float* sl = stats + (blockIdx.x & (NSLOT - 1)) * 128;
        atomicAdd(&sl[tid], s);
        atomicAdd(&sl[64 + tid], q);
    }
}

// ---------------- k_z: z[b,n] = act(h2 row) . W2[:,63] (streaming) ----------
#define ZBLK 2048
__global__ __launch_bounds__(256) void k_z(
        const float* __restrict__ h2, const float* __restrict__ bnstats,
        const float* __restrict__ gamma, const float* __restrict__ beta,
        const float* __restrict__ W2, float* __restrict__ z) {
    __shared__ float stl[128];
    __shared__ float w63[64];
    int tid = threadIdx.x;
    if (tid < 64) {
        float su = 0.f, qu = 0.f;
#pragma unroll
        for (int s = 0; s < NSLOT; ++s) {
            su += bnstats[s * 128 + tid];
            qu += bnstats[s * 128 + 64 + tid];
        }
        const float inv = 1.0f / (float)(NB * NN);
        float mu = su * inv;
        float var = qu * inv - mu * mu;
        float sc = gamma[tid] / sqrtf(var + 1e-5f);
        stl[tid] = sc;
        stl[64 + tid] = fmaf(-mu, sc, beta[tid]);
        w63[tid] = W2[tid * 64 + 63];
    }
    __syncthreads();
    int lane = tid & 63, wid = tid >> 6;
    int c4 = lane & 15;
    float4 sv = ((const float4*)stl)[c4];
    float4 tv = ((const float4*)(stl + 64))[c4];
    float4 w4 = ((const float4*)w63)[c4];
    const int total = NB * NN;   // 256B rows of h2
    for (int base = blockIdx.x * 16; base < total; base += ZBLK * 16) {
        int row = base + wid * 4 + (lane >> 4);
        float s = 0.f;
        if (row < total) {
            float4 v = ((const float4*)h2)[(size_t)row * 16 + c4];
            v.x = fmaxf(fmaf(v.x, sv.x, tv.x), 0.f);
            v.y = fmaxf(fmaf(v.y, sv.y, tv.y), 0.f);
            v.z = fmaxf(fmaf(v.z, sv.z, tv.z), 0.f);
            v.w = fmaxf(fmaf(v.w, sv.w, tv.w), 0.f);
            s = v.x * w4.x + v.y * w4.y + v.z * w4.z + v.w * w4.w;
        }
        s += __shfl_xor(s, 1);
        s += __shfl_xor(s, 2);
        s += __shfl_xor(s, 4);
        s += __shfl_xor(s, 8);
        if ((lane & 15) == 0 && row < total) z[row] = s;
    }
}

// ---------------- k_score: sparse agg of scalar z -> sc (wave per node) -----
__global__ __launch_bounds__(256) void k_score(
        const float* __restrict__ z, const float* __restrict__ b2,
        const int* __restrict__ rowptr, const int* __restrict__ csr_col,
        const float* __restrict__ csr_nv, const float* __restrict__ dinv,
        float* __restrict__ sc) {
    int tid = threadIdx.x;
    int wid = tid >> 6, lane = tid & 63;
    int g = blockIdx.x & 7;
    int nd = (blockIdx.x >> 3) * 4 + wid;   // 1250*4 = 5000 exactly
    if (nd >= NN) return;                   // no barriers below
    const float4* __restrict__ z4 = (const float4*)z + (size_t)g * NN;
    int p0 = rowptr[nd], p1 = rowptr[nd + 1];
    float4 a = {0.f, 0.f, 0.f, 0.f};
    for (int e = p0 + lane; e < p1; e += 64) {
        int col = csr_col[e];
        float nv = csr_nv[e];        // pad entries have nv=0, col=self: safe
        float4 zv = z4[col];
        fma4(a, nv, zv);
    }
#pragma unroll
    for (int off = 1; off < 64; off <<= 1) {
        a.x += __shfl_xor(a.x, off);
        a.y += __shfl_xor(a.y, off);
        a.z += __shfl_xor(a.z, off);
        a.w += __shfl_xor(a.w, off);
    }
    if (lane == 0) {
        float d = dinv[nd]; d *= d;
        float4 zs = z4[nd];
        float bb = b2[63];
        float4 o;
        o.x = fmaxf(fmaf(d, zs.x, a.x) + bb, 0.f);
        o.y = fmaxf(fmaf(d, zs.y, a.y) + bb, 0.f);
        o.z = fmaxf(fmaf(d, zs.z, a.z) + bb, 0.f);
        o.w = fmaxf(fmaf(d, zs.w, a.w) + bb, 0.f);
        ((float4*)sc)[(size_t)g * NN + nd] = o;
    }
}

// ---------------- sort-pool (blocks 0..31, barrier-free) + bnfin (block 32) --
__global__ __launch_bounds__(1024) void k_toppool(const float* __restrict__ sc, int* order,
        const float* __restrict__ stats,
        const float* __restrict__ g0, const float* __restrict__ be0,
        const float* __restrict__ g1, const float* __restrict__ be1,
        float* __restrict__ st) {
    __shared__ unsigned long long cand[16 * KPOOL];
    int tid = threadIdx.x;
    if (blockIdx.x == NB) {
        if (tid < 128) {
            int c = tid & 63, layer = tid >> 6;
            const float* sb = stats + layer * NSLOT * 128;
            float su = 0.f, qu = 0.f;
#pragma unroll
            for (int s = 0; s < NSLOT; ++s) {
                su += sb[s * 128 + c];
                qu += sb[s * 128 + 64 + c];
            }
            const float inv = 1.0f / (float)(NB * NN);
            float mu = su * inv;
            float var = qu * inv - mu * mu;
            float g = layer ? g1[c] : g0[c];
            float be = layer ? be1[c] : be0[c];
            float scv = g / sqrtf(var + 1e-5f);
            st[layer * 128 + c] = scv;
            st[layer * 128 + 64 + c] = fmaf(-mu, scv, be);
        }
        return;
    }
    int b = blockIdx.x;
    int g = b >> 2, bi = b & 3;
    int lane = tid & 63, wid = tid >> 6;
    unsigned long long key[5];
#pragma unroll
    for (int j = 0; j < 5; ++j) {
        int n = tid + j * 1024;
        unsigned long long k = 0;
        if (n < NN) {
            float v = sc[((size_t)g * NN + n) * GB + bi];   // already relu'd
            k = ((unsigned long long)__float_as_uint(v) << 32) | (unsigned int)(NN - n);
        }
        key[j] = k;
    }
    // ---- phase A: per-wave top-30 (no barriers; keys unique -> eq = owner) --
    for (int k = 0; k < KPOOL; ++k) {
        unsigned long long best = key[0];
#pragma unroll
        for (int j = 1; j < 5; ++j) best = (key[j] > best) ? key[j] : best;
#pragma unroll
        for (int off = 1; off < 64; off <<= 1) {
            unsigned long long o = __shfl_xor(best, off);
            best = (o > best) ? o : best;
        }
        if (best) {
#pragma unroll
            for (int j = 0; j < 5; ++j) if (key[j] == best) key[j] = 0;
        }
        if (lane == 0) cand[wid * KPOOL + k] = best;
    }
    __syncthreads();
    // ---- phase B: wave 0 merges 480 candidates -> global top-30 in order ----
    if (wid == 0) {
        unsigned long long r[8];
#pragma unroll
        for (int i = 0; i < 8; ++i) {
            int idx = i * 64 + lane;
            r[i] = (idx < 16 * KPOOL) ? cand[idx] : 0;
        }
        for (int k = 0; k < KPOOL; ++k) {
            unsigned long long best = r[0];
#pragma unroll
            for (int i = 1; i < 8; ++i) best = (r[i] > best) ? r[i] : best;
#pragma unroll
            for (int off = 1; off < 64; off <<= 1) {
                unsigned long long o = __shfl_xor(best, off);
                best = (o > best) ? o : best;
            }
            if (best) {
#pragma unroll
                for (int i = 0; i < 8; ++i) if (r[i] == best) r[i] = 0;
            }
            if (lane == 0) order[b * KPOOL + k] = NN - (int)(best & 0xFFFFFFFFu);
        }
    }
}

// ---------------- gather selected nodes into flat (B, 6241) ----------------
// Aggregates the h3 row for this (b,node) from act(h2) (only 960 pairs — R30),
// then the 64x64 GEMM from LDS (W2 cached in LDS — R33).
__global__ void k_gather(const float* __restrict__ xt, const float* __restrict__ h1,
                         const float* __restrict__ h2,
                         const float* __restrict__ W2, const float* __restrict__ b2,
                         const float* __restrict__ st, const float* __restrict__ age,
                         const int* __restrict__ rowptr, const int* __restrict__ csr_col,
                         const float* __restrict__ csr_nv, const float* __restrict__ dinv,
                         const int* __restrict__ order, float* __restrict__ flat) {
    __shared__ float aggP[4][64];
    __shared__ float aggRow[64];
    __shared__ float W2l[64 * 64];
    int bk = blockIdx.x;
    int b = bk / KPOOL, k = bk % KPOOL;
    int n = order[bk];
    int g = b >> 2, bi = b & 3;
    size_t node = (size_t)g * NN + n;
    int tid = threadIdx.x;
    {   // W2 -> LDS (coalesced, 4 float4 per thread)
        float4* d = (float4*)W2l;
        const float4* s = (const float4*)W2;
#pragma unroll
        for (int i = 0; i < 4; ++i) d[tid + i * 256] = s[tid + i * 256];
    }
    // ---- phase 1: 4-way edge-split aggregation of act(h2) row ----
    {
        int ep = tid >> 6, c = tid & 63;
        float sc1 = st[128 + c], sh1 = st[192 + c];
        float a = 0.f;
        if (ep == 0) {
            float d = dinv[n];
            float v = h2[(node * GB + bi) * CH + c];
            a = d * d * fmaxf(fmaf(v, sc1, sh1), 0.f);
        }
        int p0 = rowptr[n], p1 = rowptr[n + 1];
        for (int e = p0 + ep; e < p1; e += 4) {
            int col = csr_col[e];
            float nv = csr_nv[e];    // pad entries nv=0: safe
            float v = h2[(((size_t)g * NN + col) * GB + bi) * CH + c];
            a += nv * fmaxf(fmaf(v, sc1, sh1), 0.f);
        }
        aggP[ep][c] = a;
    }
    __syncthreads();
    if (tid < 64) aggRow[tid] = aggP[0][tid] + aggP[1][tid] + aggP[2][tid] + aggP[3][tid];
    __syncthreads();
    // ---- phase 2: feature assembly ----
    int f = tid;
    float val = 0.f;
    if (f < DIN) {
        val = xt[(((size_t)(b >> 3) * NN + n) * 8 + (b & 7)) * DIN + f];   // G4 layout
    } else if (f < DIN + CH) {
        int c = f - DIN;
        val = fmaxf(fmaf(h1[(node * GB + bi) * CH + c], st[c], st[64 + c]), 0.f);
    } else if (f < DIN + 2 * CH) {
        int c = f - DIN - CH;
        val = fmaxf(fmaf(h2[(node * GB + bi) * CH + c], st[128 + c], st[192 + c]), 0.f);
    } else if (f < FTOT) {
        int c = f - DIN - 2 * CH;
        float s = b2[c];
#pragma unroll 8
        for (int kk = 0; kk < 64; ++kk)
            s = fmaf(aggRow[kk], W2l[kk * 64 + c], s);
        val = fmaxf(s, 0.f);
    }
    if (f < FTOT) flat[(size_t)b * FLATW + k * FTOT + f] = val;
    if (bk == 0 && f >= FTOT && f < FTOT + NB)
        flat[(size_t)(f - FTOT) * FLATW + (FLATW - 1)] = age[f - FTOT];
}

// ---------------- MLP head layer 1: hm += flat @ mW0 (k-split, atomics) ----------------
__global__ void k_head1(const float* __restrict__ flat, const float* __restrict__ mW0,
                        float* hm) {
    int tid = threadIdx.x;
    int j4 = (tid & 31) * 4;       // 32 groups * 4 = 128 cols
    int b0 = (tid >> 5) * 4;       // 8 groups * 4 = 32 rows
    int kbase = blockIdx.x * 64;
    float acc[4][4];
#pragma unroll
    for (int i = 0; i < 4; i++)
#pragma unroll
        for (int jj = 0; jj < 4; jj++) acc[i][jj] = 0.f;
    int kend = FLATW - kbase; if (kend > 64) kend = 64;
    for (int kk = 0; kk < kend; ++kk) {
        int k = kbase + kk;
        float4 w = *(const float4*)(mW0 + (size_t)k * NH + j4);
#pragma unroll
        for (int i = 0; i < 4; i++) {
            float fv = flat[(size_t)(b0 + i) * FLATW + k];
            acc[i][0] = fmaf(fv, w.x, acc[i][0]);
            acc[i][1] = fmaf(fv, w.y, acc[i][1]);
            acc[i][2] = fmaf(fv, w.z, acc[i][2]);
            acc[i][3] = fmaf(fv, w.w, acc[i][3]);
        }
    }
#pragma unroll
    for (int i = 0; i < 4; i++)
#pragma unroll
        for (int jj = 0; jj < 4; jj++)
            atomicAdd(&hm[(size_t)(b0 + i) * NH + j4 + jj], acc[i][jj]);
}

// ---------------- head layer 2 + log_softmax (4-way j-split) ----------------
__global__ void k_head2(const float* __restrict__ hm, const float* __restrict__ mb0,
                        const float* __restrict__ mW1, const float* __restrict__ mb1,
                        float* __restrict__ out) {
    __shared__ float part[256];
    __shared__ float vals[64];
    int tid = threadIdx.x;  // 256 = 32b * 2o * 4q
    int q = tid & 3, o = (tid >> 2) & 1, b = tid >> 3;
    float acc = 0.f;
    for (int j = q * 32; j < q * 32 + 32; ++j) {
        float hv = fmaxf(hm[b * NH + j] + mb0[j], 0.f);
        acc = fmaf(hv, mW1[j * 2 + o], acc);
    }
    part[tid] = acc;
    __syncthreads();
    if (tid < 64) {
        int b2 = tid >> 1, o2 = tid & 1;
        int base = (b2 << 3) + (o2 << 2);
        vals[tid] = part[base] + part[base + 1] + part[base + 2] + part[base + 3] + mb1[o2];
    }
    __syncthreads();
    if (tid < 64) {
        int b2 = tid >> 1;
        float v0 = vals[b2 * 2], v1 = vals[b2 * 2 + 1];
        float m = fmaxf(v0, v1);
        float lse = m + logf(expf(v0 - m) + expf(v1 - m));
        out[tid] = vals[tid] - lse;
    }
}

extern "C" void kernel_launch(void* const* d_in, const int* in_sizes, int n_in,
                              void* d_out, int out_size, void* d_ws, size_t ws_size,
                              hipStream_t stream) {
    const float* x    = (const float*)d_in[0];
    const float* age  = (const float*)d_in[1];
    const float* attr = (const float*)d_in[2];
    const float* W0   = (const float*)d_in[3];
    const float* b0   = (const float*)d_in[4];
    const float* W1   = (const float*)d_in[5];
    const float* b1   = (const float*)d_in[6];
    const float* W2   = (const float*)d_in[7];
    const float* b2   = (const float*)d_in[8];
    const float* g0   = (const float*)d_in[9];
    const float* be0  = (const float*)d_in[10];
    const float* g1   = (const float*)d_in[11];
    const float* be1  = (const float*)d_in[12];
    const float* mW0  = (const float*)d_in[13];
    const float* mb0  = (const float*)d_in[14];
    const float* mW1  = (const float*)d_in[15];
    const float* mb1  = (const float*)d_in[16];
    const int* erow   = (const int*)d_in[17];
    const int* ecol   = (const int*)d_in[18];
    float* out = (float*)d_out;

    // workspace layout (floats); all float4-aligned
    float* ws     = (float*)d_ws;
    float* deg    = ws;                                  // 5008
    float* dinv   = deg + 5008;                          // 5008
    int*   counts = (int*)(dinv + 5008);                 // 5008
    int*   rowptr = counts + 5008;                       // 5008
    int*   cursor = rowptr + 5008;                       // 5008
    int*   perm   = cursor + 5008;                       // 5008
    int*   csr_col= perm + 5008;                         // NEPAD
    float* csr_nv = (float*)(csr_col + NEPAD);           // NEPAD
    float* stats  = csr_nv + NEPAD;                      // 2*32*128 = 8192
    float* st     = stats + 2 * NSLOT * 128;             // 256 (s0,t0,s1,t1)
    float* sc     = st + 256;                            // NG*NN*4 = 160000 (scores)
    int*   order  = (int*)(sc + NB * NN);                // 960
    float* flat   = (float*)(order + 960);               // 32*6241
    float* hm     = flat + (size_t)NB * FLATW;           // 4096
    float* xt     = hm + 4096;                           // (G4,N,8,16)
    float* h1     = xt + (size_t)NB * NN * DIN;          // (G8,N,4,64) each
    float* h2     = h1 + (size_t)NB * NN * CH;
    float* z      = h2 + (size_t)NB * NN * CH;           // NG*NN*4 = 160000

    // graph build: scan+sort+transpose share one dispatch (concurrent roles)
    k_init<<<32, 256, 0, stream>>>(deg, counts, stats, hm, perm);
    k_edges<<<NEB, 256, 0, stream>>>(attr, erow, deg, counts);
    k_phase1<<<2 + (NB * NN + 1023) / 1024, 1024, 0, stream>>>(counts, deg, rowptr, cursor, dinv, perm, x, xt);
    k_build<<<(NE + NN + 1023) / 1024, 1024, 0, stream>>>(erow, ecol, attr, dinv, counts, rowptr, cursor, csr_col, csr_nv);

    // conv0 (G4) + conv1 (G8, LDS W + scalar CSR); conv2 = z/score/gather-agg
    k_l16<<<NCHUNK * 4, 256, 0, stream>>>(xt, W0, b0, rowptr, csr_col, csr_nv, dinv, perm, h1, stats);
    k_l64<<<NCHUNK * NG, 256, 0, stream>>>(h1, stats, g0, be0, W1, b1, rowptr, csr_col, csr_nv, dinv, perm, h2, stats + NSLOT * 128);
    k_z<<<ZBLK, 256, 0, stream>>>(h2, stats + NSLOT * 128, g1, be1, W2, z);
    k_score<<<(NN / 4) * NG, 256, 0, stream>>>(z, b2, rowptr, csr_col, csr_nv, dinv, sc);

    // sort-pool (barrier-free, +fused bnfin) + gather (inline agg) + head
    k_toppool<<<NB + 1, 1024, 0, stream>>>(sc, order, stats, g0, be0, g1, be1, st);
    k_gather<<<NB * KPOOL, 256, 0, stream>>>(xt, h1, h2, W2, b2, st, age, rowptr, csr_col, csr_nv, dinv, order, flat);
    k_head1<<<(FLATW + 63) / 64, 256, 0, stream>>>(flat, mW0, hm);
    k_head2<<<1, 256, 0, stream>>>(hm, mb0, mW1, mb1, out);
}